// Round 1
// baseline (8110.625 us; speedup 1.0000x reference)
//
#include <hip/hip_runtime.h>

#define NPTS 30000
#define BB 4
#define R2 4096

// ---- bin index, replicating reference fp32 op order ----
__device__ __forceinline__ int coord_bin(float v){
    float t = (v + 0.5f) / 1.100001f;          // (xy+0.5)/(1.0+PAD+1e-6)
    t = fminf(fmaxf(t, 0.0f), 0.999999f);      // clip(0, 1-1e-6)
    return (int)(t * 64.0f);                   // trunc (t>=0)
}

// ---- weight transposes: make k-dim contiguous for scalar-load streaming ----
__global__ void k_prep(const float* __restrict__ fc_pos_W, const float* __restrict__ blk0W,
                       const float* __restrict__ blk1W, const float* __restrict__ blkSW,
                       const float* __restrict__ fccW, const float* __restrict__ c1W,
                       const float* __restrict__ c2W,
                       float* __restrict__ WposT, float* __restrict__ W0T, float* __restrict__ W1T,
                       float* __restrict__ WsT, float* __restrict__ WcT,
                       float* __restrict__ C1T, float* __restrict__ C2T){
    int t = blockIdx.x*256 + threadIdx.x;
    if (t < 384){ int d = t / 128, j = t % 128; WposT[t] = fc_pos_W[j*3 + d]; return; }
    t -= 384;
    if (t < 3*128*64){ int i = t / 8192; int r = t % 8192; int k = r / 64, j = r % 64;
        W0T[t] = blk0W[(i*64 + j)*128 + k]; return; }
    t -= 3*128*64;
    if (t < 3*64*64){ int i = t / 4096; int r = t % 4096; int k = r/64, j = r%64;
        W1T[t] = blk1W[(i*64+j)*64 + k]; return; }
    t -= 3*64*64;
    if (t < 3*128*64){ int i = t/8192; int r = t%8192; int k = r/64, j = r%64;
        WsT[t] = blkSW[(i*64+j)*128 + k]; return; }
    t -= 3*128*64;
    if (t < 64*256){ int k = t/256, j = t%256; WcT[t] = fccW[j*64 + k]; return; }
    t -= 64*256;
    if (t < 589824){ int c = t / 2304; int r = t % 2304; int rs = r/256, k = r%256;
        C1T[t] = c1W[(k*256 + c)*9 + rs]; return; }
    t -= 589824;
    if (t < 589824){ int c = t / 2304; int r = t % 2304; int rs = r/256, k = r%256;
        C2T[t] = c2W[(k*256 + c)*9 + rs]; return; }
}

// ---- fc_pos + plane indices. NET0 layout [B][128][N] (ch-major, coalesced) ----
__global__ void k_net0(const float* __restrict__ p, const float* __restrict__ WposT,
                       const float* __restrict__ bpos,
                       float* __restrict__ NET0, int* __restrict__ IDX){
    int pt = blockIdx.x*256 + threadIdx.x;
    int b = blockIdx.y;
    if (pt >= NPTS) return;
    const float* pp = p + ((long)b*NPTS + pt)*3;
    float p0 = pp[0], p1 = pp[1], p2 = pp[2];
    int c0 = coord_bin(p0), c1 = coord_bin(p1), c2 = coord_bin(p2);
    IDX[(0*BB + b)*NPTS + pt] = c0 + 64*c2;   // xz
    IDX[(1*BB + b)*NPTS + pt] = c0 + 64*c1;   // xy
    IDX[(2*BB + b)*NPTS + pt] = c1 + 64*c2;   // yz
    float* out = NET0 + (long)b*128*NPTS + pt;
    #pragma unroll 8
    for (int j = 0; j < 128; j++){
        float v = bpos[j] + p0*WposT[j] + p1*WposT[128+j] + p2*WposT[256+j];
        out[(long)j*NPTS] = v;
    }
}

// ---- resblock: in = concat(X1[64], X2[64]); weights scalar-streamed ----
__global__ void __launch_bounds__(256) k_res(const float* __restrict__ X1, const float* __restrict__ X2,
                      long sB1, long sB2,
                      const float* __restrict__ W0T, const float* __restrict__ b0,
                      const float* __restrict__ W1T, const float* __restrict__ b1,
                      const float* __restrict__ WsT, float* __restrict__ Y){
    int pt = blockIdx.x*256 + threadIdx.x;
    int b = blockIdx.y;
    if (pt >= NPTS) return;
    float h[64], sc[64];
    #pragma unroll
    for (int j=0;j<64;j++){ h[j] = b0[j]; sc[j] = 0.0f; }
    const float* x1 = X1 + (long)b*sB1 + pt;
    for (int k=0;k<64;k++){
        float v = x1[(long)k*NPTS];
        const float* w0 = W0T + k*64;
        const float* wsp = WsT + k*64;
        #pragma unroll
        for (int j=0;j<64;j++){ h[j] = fmaf(v, w0[j], h[j]); sc[j] = fmaf(v, wsp[j], sc[j]); }
    }
    const float* x2 = X2 + (long)b*sB2 + pt;
    for (int k=0;k<64;k++){
        float v = x2[(long)k*NPTS];
        const float* w0 = W0T + (64+k)*64;
        const float* wsp = WsT + (64+k)*64;
        #pragma unroll
        for (int j=0;j<64;j++){ h[j] = fmaf(v, w0[j], h[j]); sc[j] = fmaf(v, wsp[j], sc[j]); }
    }
    #pragma unroll
    for (int j=0;j<64;j++) h[j] = fmaxf(h[j], 0.0f);
    float* y = Y + (long)b*64*NPTS + pt;
    #pragma unroll
    for (int jg=0; jg<8; jg++){
        float t[8];
        #pragma unroll
        for (int i=0;i<8;i++) t[i] = b1[jg*8+i];
        #pragma unroll
        for (int k=0;k<64;k++){
            float hv = h[k];
            #pragma unroll
            for (int i=0;i<8;i++) t[i] = fmaf(hv, W1T[k*64 + jg*8 + i], t[i]);
        }
        #pragma unroll
        for (int i=0;i<8;i++){
            float o = sc[jg*8+i] + fmaxf(t[i], 0.0f);
            y[(long)(jg*8+i)*NPTS] = o;
        }
    }
}

__global__ void k_scatter64(const float* __restrict__ Y, const int* __restrict__ idx,
                            float* __restrict__ bins, float* __restrict__ cnt){
    int pt = blockIdx.x*256+threadIdx.x; int b = blockIdx.y;
    if (pt >= NPTS) return;
    int bin = idx[b*NPTS + pt];
    const float* y = Y + (long)b*64*NPTS + pt;
    float* g = bins + ((long)b*R2 + bin)*64;
    #pragma unroll 8
    for (int ch=0; ch<64; ch++) atomicAdd(g + ch, y[(long)ch*NPTS]);
    atomicAdd(cnt + b*R2 + bin, 1.0f);
}

__global__ void k_gather64(const float* __restrict__ bins, const float* __restrict__ cnt,
                           const int* __restrict__ idx, float* __restrict__ POOL){
    int pt = blockIdx.x*256+threadIdx.x; int b = blockIdx.y;
    if (pt >= NPTS) return;
    int bin = idx[b*NPTS + pt];
    float c = fmaxf(cnt[b*R2 + bin], 1.0f);
    const float* g = bins + ((long)b*R2 + bin)*64;
    float* o = POOL + (long)b*64*NPTS + pt;
    #pragma unroll 8
    for (int ch=0; ch<64; ch++) o[(long)ch*NPTS] = g[ch] / c;
}

// ---- fc_c: [B][64][N] -> C [B][N][256] (channel-last for scatter/sample) ----
__global__ void __launch_bounds__(256) k_fc_c(const float* __restrict__ X, const float* __restrict__ WcT,
                       const float* __restrict__ bc, float* __restrict__ C){
    int pt = blockIdx.x*256+threadIdx.x; int b = blockIdx.y; int kg = blockIdx.z;
    if (pt >= NPTS) return;
    float acc[64];
    #pragma unroll
    for (int i=0;i<64;i++) acc[i] = bc[kg*64+i];
    const float* x = X + (long)b*64*NPTS + pt;
    for (int k=0;k<64;k++){
        float v = x[(long)k*NPTS];
        const float* w = WcT + k*256 + kg*64;
        #pragma unroll
        for (int i=0;i<64;i++) acc[i] = fmaf(v, w[i], acc[i]);
    }
    float* o = C + ((long)b*NPTS + pt)*256 + kg*64;
    #pragma unroll
    for (int i=0;i<64;i++) o[i] = acc[i];
}

__global__ void k_scatter256(const float* __restrict__ C, const int* __restrict__ IDX,
                             float* __restrict__ G, float* __restrict__ cnt){
    int pt = blockIdx.x*256+threadIdx.x; int b = blockIdx.y; int pl = blockIdx.z;
    if (pt >= NPTS) return;
    int bin = IDX[(pl*BB+b)*NPTS + pt];
    const float* c = C + ((long)b*NPTS + pt)*256;
    float* g = G + ((long)(pl*BB+b)*R2 + bin)*256;
    #pragma unroll 4
    for (int ch=0; ch<256; ch++) atomicAdd(g+ch, c[ch]);
    atomicAdd(cnt + (pl*BB+b)*R2 + bin, 1.0f);
}

__global__ void k_norm256(float* __restrict__ G, const float* __restrict__ cnt){
    long t = (long)blockIdx.x*256 + threadIdx.x;     // float4 index
    if (t >= (long)12*R2*64) return;
    long cell = t / 64;
    float c = fmaxf(cnt[cell], 1.0f);
    float4* g4 = (float4*)G;
    float4 v = g4[t];
    v.x /= c; v.y /= c; v.z /= c; v.w /= c;
    g4[t] = v;
}

// ---- direct conv 3x3 SAME + relu, channel-last. Wave = 64 px (one row) x 16 ko;
//      weights wave-uniform -> scalar loads; only input goes through LDS. ----
__global__ void __launch_bounds__(256) k_conv(const float* __restrict__ IN, const float* __restrict__ WT,
                       const float* __restrict__ bias, float* __restrict__ OUT){
    __shared__ float inT[3*16*66];
    int tid = threadIdx.x;
    int lane = tid & 63;
    int ko0 = __builtin_amdgcn_readfirstlane(blockIdx.x*64 + (tid >> 6)*16);
    int y = blockIdx.y;
    int img = blockIdx.z;                  // pl*4+b
    const float* inBase = IN + (long)img*64*64*256;
    float acc[16];
    #pragma unroll
    for (int i=0;i<16;i++) acc[i] = bias[ko0+i];
    for (int cc=0; cc<16; cc++){
        if (cc) __syncthreads();
        for (int e = tid; e < 3*66*16; e += 256){
            int c = e & 15;
            int col = (e >> 4) % 66;
            int row = e / (66*16);
            int gy = y + row - 1, gx = col - 1;
            float v = 0.0f;
            if (gy >= 0 && gy < 64 && gx >= 0 && gx < 64)
                v = inBase[((long)gy*64 + gx)*256 + cc*16 + c];
            inT[(row*16 + c)*66 + col] = v;
        }
        __syncthreads();
        for (int c=0; c<16; c++){
            int cg = cc*16 + c;
            const float* w = WT + (long)cg*2304 + ko0;
            #pragma unroll
            for (int r=0; r<3; r++){
                float a0 = inT[(r*16+c)*66 + lane];
                float a1 = inT[(r*16+c)*66 + lane + 1];
                float a2 = inT[(r*16+c)*66 + lane + 2];
                const float* wr = w + r*768;
                #pragma unroll
                for (int i=0;i<16;i++){
                    acc[i] = fmaf(a0, wr[i], acc[i]);
                    acc[i] = fmaf(a1, wr[256+i], acc[i]);
                    acc[i] = fmaf(a2, wr[512+i], acc[i]);
                }
            }
        }
    }
    float* o = OUT + ((long)img*4096 + y*64 + lane)*256 + ko0;
    #pragma unroll
    for (int i=0;i<16;i++) o[i] = fmaxf(acc[i], 0.0f);
}

// ---- bilinear sample (border, align_corners=False), sum 3 planes ----
__global__ void k_sample(const float* __restrict__ A2, const float* __restrict__ query,
                         float* __restrict__ out){
    int lane = threadIdx.x & 63;
    int q = blockIdx.x*4 + (threadIdx.x >> 6);
    int b = blockIdx.y;
    const float* qp = query + ((long)b*NPTS + q)*3;
    float q0 = qp[0], q1 = qp[1], q2 = qp[2];
    float a0 = 0.f, a1 = 0.f, a2v = 0.f, a3 = 0.f;
    #pragma unroll
    for (int pl = 0; pl < 3; pl++){
        float qa = (pl==2) ? q1 : q0;     // W axis (coord a)
        float qb = (pl==1) ? q1 : q2;     // H axis (coord b)
        float gx = qa*2.0f - 1.0f, gy = qb*2.0f - 1.0f;
        float xf = ((gx + 1.0f)*64.0f - 1.0f)*0.5f;
        float yf = ((gy + 1.0f)*64.0f - 1.0f)*0.5f;
        xf = fminf(fmaxf(xf, 0.0f), 63.0f);
        yf = fminf(fmaxf(yf, 0.0f), 63.0f);
        float x0f = floorf(xf), y0f = floorf(yf);
        float wx = xf - x0f, wy = yf - y0f;
        int x0 = (int)x0f, y0 = (int)y0f;
        int x1 = min(x0+1, 63), y1 = min(y0+1, 63);
        const float* base = A2 + ((long)(pl*BB+b)*R2)*256 + lane*4;
        float4 t00 = *(const float4*)(base + (long)(y0*64+x0)*256);
        float4 t01 = *(const float4*)(base + (long)(y0*64+x1)*256);
        float4 t10 = *(const float4*)(base + (long)(y1*64+x0)*256);
        float4 t11 = *(const float4*)(base + (long)(y1*64+x1)*256);
        float w00 = (1.0f-wx)*(1.0f-wy), w01 = wx*(1.0f-wy);
        float w10 = (1.0f-wx)*wy,        w11 = wx*wy;
        a0 += t00.x*w00 + t01.x*w01 + t10.x*w10 + t11.x*w11;
        a1 += t00.y*w00 + t01.y*w01 + t10.y*w10 + t11.y*w11;
        a2v += t00.z*w00 + t01.z*w01 + t10.z*w10 + t11.z*w11;
        a3 += t00.w*w00 + t01.w*w01 + t10.w*w10 + t11.w*w11;
    }
    float4 r; r.x = a0; r.y = a1; r.z = a2v; r.w = a3;
    *(float4*)(out + ((long)b*NPTS + q)*256 + lane*4) = r;
}

extern "C" void kernel_launch(void* const* d_in, const int* in_sizes, int n_in,
                              void* d_out, int out_size, void* d_ws, size_t ws_size,
                              hipStream_t stream){
    (void)in_sizes; (void)n_in; (void)out_size; (void)ws_size;
    const float* p        = (const float*)d_in[0];
    const float* query    = (const float*)d_in[1];
    const float* fc_pos_W = (const float*)d_in[2];
    const float* fc_pos_b = (const float*)d_in[3];
    const float* blk0W    = (const float*)d_in[4];
    const float* blk0b    = (const float*)d_in[5];
    const float* blk1W    = (const float*)d_in[6];
    const float* blk1b    = (const float*)d_in[7];
    const float* blkSW    = (const float*)d_in[8];
    const float* fccW     = (const float*)d_in[9];
    const float* fccB     = (const float*)d_in[10];
    const float* c1W      = (const float*)d_in[11];
    const float* c1b      = (const float*)d_in[12];
    const float* c2W      = (const float*)d_in[13];
    const float* c2b      = (const float*)d_in[14];

    char* ws = (char*)d_ws;
    size_t off = 0;
    auto alloc = [&](size_t bytes)->char*{
        char* r = ws + off; off = (off + bytes + 255) & ~(size_t)255; return r; };
    float* WposT = (float*)alloc(384*4);
    float* W0T   = (float*)alloc(24576*4);
    float* W1T   = (float*)alloc(12288*4);
    float* WsT   = (float*)alloc(24576*4);
    float* WcT   = (float*)alloc(16384*4);
    float* C1T   = (float*)alloc(589824UL*4);
    float* C2T   = (float*)alloc(589824UL*4);
    int*   IDX   = (int*)  alloc(3UL*BB*NPTS*4);
    float* Rg    = (float*)alloc(30720000UL*4);   // NET0 | Yb | POOL, aliased by C
    float* NET0  = Rg;
    float* Yb    = Rg + 15360000UL;
    float* POOL  = Rg + 23040000UL;
    float* C     = Rg;
    float* Ya    = (float*)alloc(7680000UL*4);
    float* bins  = (float*)alloc((1048576UL + 16384UL)*4);
    float* cnt64 = bins + 1048576UL;
    float* G     = (float*)alloc((12582912UL + 49152UL)*4);
    float* cnt256 = G + 12582912UL;
    float* A1    = (float*)alloc(12582912UL*4);
    float* A2    = G;   // G dead after conv1 -> reuse for conv2 output

    dim3 blk(256);
    k_prep<<<4914, blk, 0, stream>>>(fc_pos_W, blk0W, blk1W, blkSW, fccW, c1W, c2W,
                                     WposT, W0T, W1T, WsT, WcT, C1T, C2T);
    k_net0<<<dim3(118, BB), blk, 0, stream>>>(p, WposT, fc_pos_b, NET0, IDX);
    // resblock 0 (input = NET0[0:64] ++ NET0[64:128])
    k_res<<<dim3(118,BB), blk, 0, stream>>>(NET0, NET0 + 64UL*NPTS, 128UL*NPTS, 128UL*NPTS,
                                            W0T, blk0b, W1T, blk1b, WsT, Ya);
    // pooling round 1 (xz bins)
    hipMemsetAsync(bins, 0, (1048576UL+16384UL)*4, stream);
    k_scatter64<<<dim3(118,BB), blk, 0, stream>>>(Ya, IDX, bins, cnt64);
    k_gather64 <<<dim3(118,BB), blk, 0, stream>>>(bins, cnt64, IDX, POOL);
    k_res<<<dim3(118,BB), blk, 0, stream>>>(Ya, POOL, 64UL*NPTS, 64UL*NPTS,
                                            W0T + 8192, blk0b + 64, W1T + 4096, blk1b + 64,
                                            WsT + 8192, Yb);
    // pooling round 2
    hipMemsetAsync(bins, 0, (1048576UL+16384UL)*4, stream);
    k_scatter64<<<dim3(118,BB), blk, 0, stream>>>(Yb, IDX, bins, cnt64);
    k_gather64 <<<dim3(118,BB), blk, 0, stream>>>(bins, cnt64, IDX, POOL);
    k_res<<<dim3(118,BB), blk, 0, stream>>>(Yb, POOL, 64UL*NPTS, 64UL*NPTS,
                                            W0T + 16384, blk0b + 128, W1T + 8192, blk1b + 128,
                                            WsT + 16384, Ya);
    // fc_c -> C [B][N][256]  (overwrites NET0/Yb/POOL region; all dead)
    k_fc_c<<<dim3(118,BB,4), blk, 0, stream>>>(Ya, WcT, fccB, C);
    // plane scatter-mean
    hipMemsetAsync(G, 0, (12582912UL+49152UL)*4, stream);
    k_scatter256<<<dim3(118,BB,3), blk, 0, stream>>>(C, IDX, G, cnt256);
    k_norm256<<<12288, blk, 0, stream>>>(G, cnt256);
    // convs (12 images = 3 planes x 4 batches each)
    k_conv<<<dim3(4,64,12), blk, 0, stream>>>(G,  C1T, c1b, A1);
    k_conv<<<dim3(4,64,12), blk, 0, stream>>>(A1, C2T, c2b, A2);
    // bilinear sample + plane sum -> out [B][Nq][256]
    k_sample<<<dim3(7500,BB), blk, 0, stream>>>(A2, query, (float*)d_out);
}

// Round 2
// 2479.204 us; speedup vs baseline: 3.2715x; 3.2715x over previous
//
#include <hip/hip_runtime.h>

#define NPTS 30000
#define BB 4
#define R2 4096
#define NIMG 12

// ---- bin index, replicating reference fp32 op order ----
__device__ __forceinline__ int coord_bin(float v){
    float t = (v + 0.5f) / 1.100001f;          // (xy+0.5)/(1.0+PAD+1e-6)
    t = fminf(fmaxf(t, 0.0f), 0.999999f);      // clip(0, 1-1e-6)
    return (int)(t * 64.0f);                   // trunc (t>=0)
}

// ---- weight transposes: make k-dim contiguous for scalar-load streaming ----
__global__ void k_prep(const float* __restrict__ fc_pos_W, const float* __restrict__ blk0W,
                       const float* __restrict__ blk1W, const float* __restrict__ blkSW,
                       const float* __restrict__ fccW, const float* __restrict__ c1W,
                       const float* __restrict__ c2W,
                       float* __restrict__ WposT, float* __restrict__ W0T, float* __restrict__ W1T,
                       float* __restrict__ WsT, float* __restrict__ WcT,
                       float* __restrict__ C1T, float* __restrict__ C2T){
    int t = blockIdx.x*256 + threadIdx.x;
    if (t < 384){ int d = t / 128, j = t % 128; WposT[t] = fc_pos_W[j*3 + d]; return; }
    t -= 384;
    if (t < 3*128*64){ int i = t / 8192; int r = t % 8192; int k = r / 64, j = r % 64;
        W0T[t] = blk0W[(i*64 + j)*128 + k]; return; }
    t -= 3*128*64;
    if (t < 3*64*64){ int i = t / 4096; int r = t % 4096; int k = r/64, j = r%64;
        W1T[t] = blk1W[(i*64+j)*64 + k]; return; }
    t -= 3*64*64;
    if (t < 3*128*64){ int i = t/8192; int r = t%8192; int k = r/64, j = r%64;
        WsT[t] = blkSW[(i*64+j)*128 + k]; return; }
    t -= 3*128*64;
    if (t < 64*256){ int k = t/256, j = t%256; WcT[t] = fccW[j*64 + k]; return; }
    t -= 64*256;
    if (t < 589824){ int c = t / 2304; int r = t % 2304; int rs = r/256, k = r%256;
        C1T[t] = c1W[(k*256 + c)*9 + rs]; return; }
    t -= 589824;
    if (t < 589824){ int c = t / 2304; int r = t % 2304; int rs = r/256, k = r%256;
        C2T[t] = c2W[(k*256 + c)*9 + rs]; return; }
}

// ---- fc_pos + plane indices. NET0 layout [B][N][128] (channel-last) ----
__global__ void k_net0(const float* __restrict__ p, const float* __restrict__ WposT,
                       const float* __restrict__ bpos,
                       float* __restrict__ NET0, int* __restrict__ IDX){
    int pt = blockIdx.x*256 + threadIdx.x;
    int b = blockIdx.y;
    if (pt >= NPTS) return;
    const float* pp = p + ((long)b*NPTS + pt)*3;
    float p0 = pp[0], p1 = pp[1], p2 = pp[2];
    int c0 = coord_bin(p0), c1 = coord_bin(p1), c2 = coord_bin(p2);
    IDX[(0*BB + b)*NPTS + pt] = c0 + 64*c2;   // xz
    IDX[(1*BB + b)*NPTS + pt] = c0 + 64*c1;   // xy
    IDX[(2*BB + b)*NPTS + pt] = c1 + 64*c2;   // yz
    float* out = NET0 + ((long)b*NPTS + pt)*128;
    #pragma unroll
    for (int j = 0; j < 128; j += 4){
        float4 v;
        v.x = bpos[j+0] + p0*WposT[j+0] + p1*WposT[128+j+0] + p2*WposT[256+j+0];
        v.y = bpos[j+1] + p0*WposT[j+1] + p1*WposT[128+j+1] + p2*WposT[256+j+1];
        v.z = bpos[j+2] + p0*WposT[j+2] + p1*WposT[128+j+2] + p2*WposT[256+j+2];
        v.w = bpos[j+3] + p0*WposT[j+3] + p1*WposT[128+j+3] + p2*WposT[256+j+3];
        *(float4*)(out + j) = v;
    }
}

// ---- counting sort of points into bins (per image) ----
__global__ void k_hist(const int* __restrict__ IDX, int* __restrict__ hist){
    int t = blockIdx.x*256 + threadIdx.x;
    if (t >= NIMG*NPTS) return;
    int img = t / NPTS;
    atomicAdd(&hist[img*R2 + IDX[t]], 1);
}

__global__ void k_scan(const int* __restrict__ hist, int* __restrict__ binStart,
                       int* __restrict__ cursor){
    __shared__ int sums[256];
    int img = blockIdx.x; int tid = threadIdx.x;
    int v[16]; int s = 0;
    const int* h = hist + img*R2 + tid*16;
    #pragma unroll
    for (int i=0;i<16;i++){ v[i] = s; s += h[i]; }
    sums[tid] = s;
    __syncthreads();
    for (int d=1; d<256; d<<=1){
        int t = (tid>=d)? sums[tid-d] : 0;
        __syncthreads();
        sums[tid] += t;
        __syncthreads();
    }
    int base = (tid==0)? 0 : sums[tid-1];
    int* bs = binStart + img*R2 + tid*16;
    int* cu = cursor  + img*R2 + tid*16;
    #pragma unroll
    for (int i=0;i<16;i++){ bs[i] = base + v[i]; cu[i] = base + v[i]; }
}

__global__ void k_mklist(const int* __restrict__ IDX, int* __restrict__ cursor,
                         int* __restrict__ plist){
    int t = blockIdx.x*256 + threadIdx.x;
    if (t >= NIMG*NPTS) return;
    int img = t / NPTS; int pt = t - img*NPTS;
    int bin = IDX[t];
    int pos = atomicAdd(&cursor[img*R2 + bin], 1);
    plist[img*NPTS + pos] = pt;
}

// ---- resblock: in = concat(X1[64], X2[64]) channel-last; weights scalar-streamed ----
__global__ void __launch_bounds__(256) k_res(const float* __restrict__ X1, const float* __restrict__ X2,
                      int s1, int s2,
                      const float* __restrict__ W0T, const float* __restrict__ b0,
                      const float* __restrict__ W1T, const float* __restrict__ b1,
                      const float* __restrict__ WsT, float* __restrict__ Y){
    int pt = blockIdx.x*256 + threadIdx.x;
    int b = blockIdx.y;
    if (pt >= NPTS) return;
    float h[64], sc[64];
    #pragma unroll
    for (int j=0;j<64;j++){ h[j] = b0[j]; sc[j] = 0.0f; }
    const float* x1 = X1 + ((long)b*NPTS + pt)*s1;
    for (int kk=0;kk<64;kk+=4){
        float4 xv = *(const float4*)(x1 + kk);
        float vv[4] = {xv.x, xv.y, xv.z, xv.w};
        #pragma unroll
        for (int u=0;u<4;u++){
            float v = vv[u];
            const float* w0 = W0T + (kk+u)*64;
            const float* wsp = WsT + (kk+u)*64;
            #pragma unroll
            for (int j=0;j<64;j++){ h[j] = fmaf(v, w0[j], h[j]); sc[j] = fmaf(v, wsp[j], sc[j]); }
        }
    }
    const float* x2 = X2 + ((long)b*NPTS + pt)*s2;
    for (int kk=0;kk<64;kk+=4){
        float4 xv = *(const float4*)(x2 + kk);
        float vv[4] = {xv.x, xv.y, xv.z, xv.w};
        #pragma unroll
        for (int u=0;u<4;u++){
            float v = vv[u];
            const float* w0 = W0T + (64+kk+u)*64;
            const float* wsp = WsT + (64+kk+u)*64;
            #pragma unroll
            for (int j=0;j<64;j++){ h[j] = fmaf(v, w0[j], h[j]); sc[j] = fmaf(v, wsp[j], sc[j]); }
        }
    }
    #pragma unroll
    for (int j=0;j<64;j++) h[j] = fmaxf(h[j], 0.0f);
    float* y = Y + ((long)b*NPTS + pt)*64;
    #pragma unroll
    for (int jg=0; jg<8; jg++){
        float t[8];
        #pragma unroll
        for (int i=0;i<8;i++) t[i] = b1[jg*8+i];
        #pragma unroll
        for (int k=0;k<64;k++){
            float hv = h[k];
            #pragma unroll
            for (int i=0;i<8;i++) t[i] = fmaf(hv, W1T[k*64 + jg*8 + i], t[i]);
        }
        #pragma unroll
        for (int i=0;i<8;i++) y[jg*8+i] = sc[jg*8+i] + fmaxf(t[i], 0.0f);
    }
}

// ---- pooling: wave per (b,bin); lane=channel; mean then broadcast to member points ----
__global__ void k_poolgather(const float* __restrict__ Y, const int* __restrict__ plist,
                             const int* __restrict__ binStart, const int* __restrict__ hist,
                             float* __restrict__ POOL){
    int tid = threadIdx.x; int lane = tid & 63; int wv = tid >> 6;
    int g = blockIdx.x*4 + wv;          // (b,bin) over 4*4096
    int b = g >> 12; int bl = g & 4095;
    int idx = b*R2 + bl;                // xz-plane image index = b
    int start = binStart[idx]; int cnt = hist[idx];
    const int* pl = plist + b*NPTS;
    float s = 0.0f;
    for (int i=0;i<cnt;i++){
        int pt = pl[start+i];
        s += Y[((long)b*NPTS + pt)*64 + lane];
    }
    s /= fmaxf((float)cnt, 1.0f);
    for (int i=0;i<cnt;i++){
        int pt = pl[start+i];
        POOL[((long)b*NPTS + pt)*64 + lane] = s;
    }
}

// ---- fc_c: [B][N][64] -> C [B][N][256] ----
__global__ void __launch_bounds__(256) k_fc_c(const float* __restrict__ X, const float* __restrict__ WcT,
                       const float* __restrict__ bc, float* __restrict__ C){
    int pt = blockIdx.x*256 + threadIdx.x; int b = blockIdx.y; int kg = blockIdx.z;
    if (pt >= NPTS) return;
    float acc[64];
    #pragma unroll
    for (int i=0;i<64;i++) acc[i] = bc[kg*64+i];
    const float* x = X + ((long)b*NPTS + pt)*64;
    for (int kk=0;kk<64;kk+=4){
        float4 xv = *(const float4*)(x + kk);
        float vv[4] = {xv.x, xv.y, xv.z, xv.w};
        #pragma unroll
        for (int u=0;u<4;u++){
            float v = vv[u];
            const float* w = WcT + (kk+u)*256 + kg*64;
            #pragma unroll
            for (int i=0;i<64;i++) acc[i] = fmaf(v, w[i], acc[i]);
        }
    }
    float* o = C + ((long)b*NPTS + pt)*256 + kg*64;
    #pragma unroll
    for (int i=0;i<64;i+=4){
        float4 v; v.x=acc[i]; v.y=acc[i+1]; v.z=acc[i+2]; v.w=acc[i+3];
        *(float4*)(o + i) = v;
    }
}

// ---- plane scatter-mean as sorted gather: wave per (img,bin), lane = 4 channels ----
__global__ void k_gatherC(const float* __restrict__ C, const int* __restrict__ plist,
                          const int* __restrict__ binStart, const int* __restrict__ hist,
                          float* __restrict__ G){
    int tid = threadIdx.x; int lane = tid & 63; int wv = tid >> 6;
    int g = blockIdx.x*4 + wv;          // (img,bin) over 12*4096
    int img = g >> 12; int bl = g & 4095;
    int b = img & 3;
    int idx = img*R2 + bl;
    int start = binStart[idx]; int cnt = hist[idx];
    const int* pl = plist + img*NPTS;
    float4 acc = {0.f,0.f,0.f,0.f};
    const float* Cb = C + (long)b*NPTS*256 + lane*4;
    for (int i=0;i<cnt;i++){
        int pt = pl[start+i];
        float4 v = *(const float4*)(Cb + (long)pt*256);
        acc.x += v.x; acc.y += v.y; acc.z += v.z; acc.w += v.w;
    }
    float inv = 1.0f / fmaxf((float)cnt, 1.0f);
    acc.x *= inv; acc.y *= inv; acc.z *= inv; acc.w *= inv;
    *(float4*)(G + ((long)img*R2 + bl)*256 + lane*4) = acc;
}

// ---- direct conv 3x3 SAME + relu, channel-last. Wave = 64 px (one row) x 16 ko ----
__global__ void __launch_bounds__(256) k_conv(const float* __restrict__ IN, const float* __restrict__ WT,
                       const float* __restrict__ bias, float* __restrict__ OUT){
    __shared__ float inT[3*16*66];
    int tid = threadIdx.x;
    int lane = tid & 63;
    int ko0 = __builtin_amdgcn_readfirstlane(blockIdx.x*64 + (tid >> 6)*16);
    int y = blockIdx.y;
    int img = blockIdx.z;
    const float* inBase = IN + (long)img*64*64*256;
    float acc[16];
    #pragma unroll
    for (int i=0;i<16;i++) acc[i] = bias[ko0+i];
    for (int cc=0; cc<16; cc++){
        if (cc) __syncthreads();
        for (int e = tid; e < 3*66*16; e += 256){
            int c = e & 15;
            int col = (e >> 4) % 66;
            int row = e / (66*16);
            int gy = y + row - 1, gx = col - 1;
            float v = 0.0f;
            if (gy >= 0 && gy < 64 && gx >= 0 && gx < 64)
                v = inBase[((long)gy*64 + gx)*256 + cc*16 + c];
            inT[(row*16 + c)*66 + col] = v;
        }
        __syncthreads();
        for (int c=0; c<16; c++){
            int cg = cc*16 + c;
            const float* w = WT + (long)cg*2304 + ko0;
            #pragma unroll
            for (int r=0; r<3; r++){
                float a0 = inT[(r*16+c)*66 + lane];
                float a1 = inT[(r*16+c)*66 + lane + 1];
                float a2 = inT[(r*16+c)*66 + lane + 2];
                const float* wr = w + r*768;
                #pragma unroll
                for (int i=0;i<16;i++){
                    acc[i] = fmaf(a0, wr[i], acc[i]);
                    acc[i] = fmaf(a1, wr[256+i], acc[i]);
                    acc[i] = fmaf(a2, wr[512+i], acc[i]);
                }
            }
        }
    }
    float* o = OUT + ((long)img*4096 + y*64 + lane)*256 + ko0;
    #pragma unroll
    for (int i=0;i<16;i++) o[i] = fmaxf(acc[i], 0.0f);
}

// ---- bilinear sample (border, align_corners=False), sum 3 planes ----
__global__ void k_sample(const float* __restrict__ A2, const float* __restrict__ query,
                         float* __restrict__ out){
    int lane = threadIdx.x & 63;
    int q = blockIdx.x*4 + (threadIdx.x >> 6);
    int b = blockIdx.y;
    const float* qp = query + ((long)b*NPTS + q)*3;
    float q0 = qp[0], q1 = qp[1], q2 = qp[2];
    float a0 = 0.f, a1 = 0.f, a2v = 0.f, a3 = 0.f;
    #pragma unroll
    for (int pl = 0; pl < 3; pl++){
        float qa = (pl==2) ? q1 : q0;
        float qb = (pl==1) ? q1 : q2;
        float gx = qa*2.0f - 1.0f, gy = qb*2.0f - 1.0f;
        float xf = ((gx + 1.0f)*64.0f - 1.0f)*0.5f;
        float yf = ((gy + 1.0f)*64.0f - 1.0f)*0.5f;
        xf = fminf(fmaxf(xf, 0.0f), 63.0f);
        yf = fminf(fmaxf(yf, 0.0f), 63.0f);
        float x0f = floorf(xf), y0f = floorf(yf);
        float wx = xf - x0f, wy = yf - y0f;
        int x0 = (int)x0f, y0 = (int)y0f;
        int x1 = min(x0+1, 63), y1 = min(y0+1, 63);
        const float* base = A2 + ((long)(pl*BB+b)*R2)*256 + lane*4;
        float4 t00 = *(const float4*)(base + (long)(y0*64+x0)*256);
        float4 t01 = *(const float4*)(base + (long)(y0*64+x1)*256);
        float4 t10 = *(const float4*)(base + (long)(y1*64+x0)*256);
        float4 t11 = *(const float4*)(base + (long)(y1*64+x1)*256);
        float w00 = (1.0f-wx)*(1.0f-wy), w01 = wx*(1.0f-wy);
        float w10 = (1.0f-wx)*wy,        w11 = wx*wy;
        a0  += t00.x*w00 + t01.x*w01 + t10.x*w10 + t11.x*w11;
        a1  += t00.y*w00 + t01.y*w01 + t10.y*w10 + t11.y*w11;
        a2v += t00.z*w00 + t01.z*w01 + t10.z*w10 + t11.z*w11;
        a3  += t00.w*w00 + t01.w*w01 + t10.w*w10 + t11.w*w11;
    }
    float4 r; r.x = a0; r.y = a1; r.z = a2v; r.w = a3;
    *(float4*)(out + ((long)b*NPTS + q)*256 + lane*4) = r;
}

extern "C" void kernel_launch(void* const* d_in, const int* in_sizes, int n_in,
                              void* d_out, int out_size, void* d_ws, size_t ws_size,
                              hipStream_t stream){
    (void)in_sizes; (void)n_in; (void)out_size; (void)ws_size;
    const float* p        = (const float*)d_in[0];
    const float* query    = (const float*)d_in[1];
    const float* fc_pos_W = (const float*)d_in[2];
    const float* fc_pos_b = (const float*)d_in[3];
    const float* blk0W    = (const float*)d_in[4];
    const float* blk0b    = (const float*)d_in[5];
    const float* blk1W    = (const float*)d_in[6];
    const float* blk1b    = (const float*)d_in[7];
    const float* blkSW    = (const float*)d_in[8];
    const float* fccW     = (const float*)d_in[9];
    const float* fccB     = (const float*)d_in[10];
    const float* c1W      = (const float*)d_in[11];
    const float* c1b      = (const float*)d_in[12];
    const float* c2W      = (const float*)d_in[13];
    const float* c2b      = (const float*)d_in[14];

    char* ws = (char*)d_ws;
    size_t off = 0;
    auto alloc = [&](size_t bytes)->char*{
        char* r = ws + off; off = (off + bytes + 255) & ~(size_t)255; return r; };
    float* WposT = (float*)alloc(384*4);
    float* W0T   = (float*)alloc(24576*4);
    float* W1T   = (float*)alloc(12288*4);
    float* WsT   = (float*)alloc(24576*4);
    float* WcT   = (float*)alloc(16384*4);
    float* C1T   = (float*)alloc(589824UL*4);
    float* C2T   = (float*)alloc(589824UL*4);
    int*   IDX   = (int*)  alloc((size_t)NIMG*NPTS*4);
    int*   hist  = (int*)  alloc((size_t)NIMG*R2*4);
    int*   binStart = (int*)alloc((size_t)NIMG*R2*4);
    int*   cursor   = (int*)alloc((size_t)NIMG*R2*4);
    int*   plist    = (int*)alloc((size_t)NIMG*NPTS*4);
    // Rg packs NET0[15.36M] | POOL[7.68M] | Yb[7.68M]; C aliases the whole 30.72M
    float* Rg    = (float*)alloc(30720000UL*4);
    float* NET0  = Rg;
    float* POOL  = Rg + 15360000UL;
    float* Yb    = Rg + 23040000UL;
    float* C     = Rg;
    float* Ya    = (float*)alloc(7680000UL*4);
    float* G     = (float*)alloc(12582912UL*4);
    float* A1    = (float*)alloc(12582912UL*4);
    float* A2    = G;   // G dead after conv1 -> reuse for conv2 output

    dim3 blk(256);
    k_prep<<<4914, blk, 0, stream>>>(fc_pos_W, blk0W, blk1W, blkSW, fccW, c1W, c2W,
                                     WposT, W0T, W1T, WsT, WcT, C1T, C2T);
    k_net0<<<dim3(118, BB), blk, 0, stream>>>(p, WposT, fc_pos_b, NET0, IDX);
    // counting sort of points into bins, all 12 images
    hipMemsetAsync(hist, 0, (size_t)NIMG*R2*4, stream);
    k_hist  <<<(NIMG*NPTS + 255)/256, blk, 0, stream>>>(IDX, hist);
    k_scan  <<<NIMG, blk, 0, stream>>>(hist, binStart, cursor);
    k_mklist<<<(NIMG*NPTS + 255)/256, blk, 0, stream>>>(IDX, cursor, plist);
    // resblock 0
    k_res<<<dim3(118,BB), blk, 0, stream>>>(NET0, NET0 + 64, 128, 128,
                                            W0T, blk0b, W1T, blk1b, WsT, Ya);
    // pooling round 1 (xz bins = image b)
    k_poolgather<<<4096, blk, 0, stream>>>(Ya, plist, binStart, hist, POOL);
    k_res<<<dim3(118,BB), blk, 0, stream>>>(Ya, POOL, 64, 64,
                                            W0T + 8192, blk0b + 64, W1T + 4096, blk1b + 64,
                                            WsT + 8192, Yb);
    // pooling round 2
    k_poolgather<<<4096, blk, 0, stream>>>(Yb, plist, binStart, hist, POOL);
    k_res<<<dim3(118,BB), blk, 0, stream>>>(Yb, POOL, 64, 64,
                                            W0T + 16384, blk0b + 128, W1T + 8192, blk1b + 128,
                                            WsT + 16384, Ya);
    // fc_c -> C [B][N][256]  (overwrites NET0/POOL/Yb; all dead)
    k_fc_c<<<dim3(118,BB,4), blk, 0, stream>>>(Ya, WcT, fccB, C);
    // plane scatter-mean as sorted bin gather (fused normalize, no memset)
    k_gatherC<<<12288, blk, 0, stream>>>(C, plist, binStart, hist, G);
    // convs (12 images)
    k_conv<<<dim3(4,64,12), blk, 0, stream>>>(G,  C1T, c1b, A1);
    k_conv<<<dim3(4,64,12), blk, 0, stream>>>(A1, C2T, c2b, A2);
    // bilinear sample + plane sum
    k_sample<<<dim3(7500,BB), blk, 0, stream>>>(A2, query, (float*)d_out);
}

// Round 3
// 1200.692 us; speedup vs baseline: 6.7550x; 2.0648x over previous
//
#include <hip/hip_runtime.h>

#define NPTS 30000
#define BB 4
#define R2 4096
#define NIMG 12

typedef __attribute__((ext_vector_type(8))) short short8;
typedef __attribute__((ext_vector_type(4))) float floatx4;

__device__ __forceinline__ ushort f2bf(float x){
    union { float f; unsigned u; } v; v.f = x;
    unsigned r = (v.u + 0x7fffu + ((v.u >> 16) & 1u)) >> 16;   // RNE
    return (ushort)r;
}

// ---- bin index, replicating reference fp32 op order ----
__device__ __forceinline__ int coord_bin(float v){
    float t = (v + 0.5f) / 1.100001f;
    t = fminf(fmaxf(t, 0.0f), 0.999999f);
    return (int)(t * 64.0f);
}

// ---- weight prep: MLP weights transposed fp32; conv weights -> bf16 [tap][ko][ci] ----
__global__ void k_prep(const float* __restrict__ fc_pos_W, const float* __restrict__ blk0W,
                       const float* __restrict__ blk1W, const float* __restrict__ blkSW,
                       const float* __restrict__ fccW, const float* __restrict__ c1W,
                       const float* __restrict__ c2W,
                       float* __restrict__ WposT, float* __restrict__ W0T, float* __restrict__ W1T,
                       float* __restrict__ WsT, float* __restrict__ WcT,
                       ushort* __restrict__ WB1, ushort* __restrict__ WB2){
    int t = blockIdx.x*256 + threadIdx.x;
    if (t < 384){ int d = t / 128, j = t % 128; WposT[t] = fc_pos_W[j*3 + d]; return; }
    t -= 384;
    if (t < 3*128*64){ int i = t / 8192; int r = t % 8192; int k = r / 64, j = r % 64;
        W0T[t] = blk0W[(i*64 + j)*128 + k]; return; }
    t -= 3*128*64;
    if (t < 3*64*64){ int i = t / 4096; int r = t % 4096; int k = r/64, j = r%64;
        W1T[t] = blk1W[(i*64+j)*64 + k]; return; }
    t -= 3*64*64;
    if (t < 3*128*64){ int i = t/8192; int r = t%8192; int k = r/64, j = r%64;
        WsT[t] = blkSW[(i*64+j)*128 + k]; return; }
    t -= 3*128*64;
    if (t < 64*256){ int k = t/256, j = t%256; WcT[t] = fccW[j*64 + k]; return; }
    t -= 64*256;
    if (t < 589824){ int tap = t/65536; int rem = t%65536; int ko = rem/256; int ci = rem%256;
        WB1[t] = f2bf(c1W[(ko*256+ci)*9 + tap]); return; }
    t -= 589824;
    if (t < 589824){ int tap = t/65536; int rem = t%65536; int ko = rem/256; int ci = rem%256;
        WB2[t] = f2bf(c2W[(ko*256+ci)*9 + tap]); return; }
}

// ---- fc_pos + plane indices. NET0 layout [B][N][128] (channel-last) ----
__global__ void k_net0(const float* __restrict__ p, const float* __restrict__ WposT,
                       const float* __restrict__ bpos,
                       float* __restrict__ NET0, int* __restrict__ IDX){
    int pt = blockIdx.x*256 + threadIdx.x;
    int b = blockIdx.y;
    if (pt >= NPTS) return;
    const float* pp = p + ((long)b*NPTS + pt)*3;
    float p0 = pp[0], p1 = pp[1], p2 = pp[2];
    int c0 = coord_bin(p0), c1 = coord_bin(p1), c2 = coord_bin(p2);
    IDX[(0*BB + b)*NPTS + pt] = c0 + 64*c2;   // xz
    IDX[(1*BB + b)*NPTS + pt] = c0 + 64*c1;   // xy
    IDX[(2*BB + b)*NPTS + pt] = c1 + 64*c2;   // yz
    float* out = NET0 + ((long)b*NPTS + pt)*128;
    #pragma unroll
    for (int j = 0; j < 128; j += 4){
        float4 v;
        v.x = bpos[j+0] + p0*WposT[j+0] + p1*WposT[128+j+0] + p2*WposT[256+j+0];
        v.y = bpos[j+1] + p0*WposT[j+1] + p1*WposT[128+j+1] + p2*WposT[256+j+1];
        v.z = bpos[j+2] + p0*WposT[j+2] + p1*WposT[128+j+2] + p2*WposT[256+j+2];
        v.w = bpos[j+3] + p0*WposT[j+3] + p1*WposT[128+j+3] + p2*WposT[256+j+3];
        *(float4*)(out + j) = v;
    }
}

// ---- counting sort of points into bins (per image) ----
__global__ void k_hist(const int* __restrict__ IDX, int* __restrict__ hist){
    int t = blockIdx.x*256 + threadIdx.x;
    if (t >= NIMG*NPTS) return;
    int img = t / NPTS;
    atomicAdd(&hist[img*R2 + IDX[t]], 1);
}

__global__ void k_scan(const int* __restrict__ hist, int* __restrict__ binStart,
                       int* __restrict__ cursor){
    __shared__ int sums[256];
    int img = blockIdx.x; int tid = threadIdx.x;
    int v[16]; int s = 0;
    const int* h = hist + img*R2 + tid*16;
    #pragma unroll
    for (int i=0;i<16;i++){ v[i] = s; s += h[i]; }
    sums[tid] = s;
    __syncthreads();
    for (int d=1; d<256; d<<=1){
        int t = (tid>=d)? sums[tid-d] : 0;
        __syncthreads();
        sums[tid] += t;
        __syncthreads();
    }
    int base = (tid==0)? 0 : sums[tid-1];
    int* bs = binStart + img*R2 + tid*16;
    int* cu = cursor  + img*R2 + tid*16;
    #pragma unroll
    for (int i=0;i<16;i++){ bs[i] = base + v[i]; cu[i] = base + v[i]; }
}

__global__ void k_mklist(const int* __restrict__ IDX, int* __restrict__ cursor,
                         int* __restrict__ plist){
    int t = blockIdx.x*256 + threadIdx.x;
    if (t >= NIMG*NPTS) return;
    int img = t / NPTS; int pt = t - img*NPTS;
    int bin = IDX[t];
    int pos = atomicAdd(&cursor[img*R2 + bin], 1);
    plist[img*NPTS + pos] = pt;
}

// ---- resblock: in = concat(X1[64], X2[64]) channel-last; weights scalar-streamed ----
__global__ void __launch_bounds__(256) k_res(const float* __restrict__ X1, const float* __restrict__ X2,
                      int s1, int s2,
                      const float* __restrict__ W0T, const float* __restrict__ b0,
                      const float* __restrict__ W1T, const float* __restrict__ b1,
                      const float* __restrict__ WsT, float* __restrict__ Y){
    int pt = blockIdx.x*256 + threadIdx.x;
    int b = blockIdx.y;
    if (pt >= NPTS) return;
    float h[64], sc[64];
    #pragma unroll
    for (int j=0;j<64;j++){ h[j] = b0[j]; sc[j] = 0.0f; }
    const float* x1 = X1 + ((long)b*NPTS + pt)*s1;
    for (int kk=0;kk<64;kk+=4){
        float4 xv = *(const float4*)(x1 + kk);
        float vv[4] = {xv.x, xv.y, xv.z, xv.w};
        #pragma unroll
        for (int u=0;u<4;u++){
            float v = vv[u];
            const float* w0 = W0T + (kk+u)*64;
            const float* wsp = WsT + (kk+u)*64;
            #pragma unroll
            for (int j=0;j<64;j++){ h[j] = fmaf(v, w0[j], h[j]); sc[j] = fmaf(v, wsp[j], sc[j]); }
        }
    }
    const float* x2 = X2 + ((long)b*NPTS + pt)*s2;
    for (int kk=0;kk<64;kk+=4){
        float4 xv = *(const float4*)(x2 + kk);
        float vv[4] = {xv.x, xv.y, xv.z, xv.w};
        #pragma unroll
        for (int u=0;u<4;u++){
            float v = vv[u];
            const float* w0 = W0T + (64+kk+u)*64;
            const float* wsp = WsT + (64+kk+u)*64;
            #pragma unroll
            for (int j=0;j<64;j++){ h[j] = fmaf(v, w0[j], h[j]); sc[j] = fmaf(v, wsp[j], sc[j]); }
        }
    }
    #pragma unroll
    for (int j=0;j<64;j++) h[j] = fmaxf(h[j], 0.0f);
    float* y = Y + ((long)b*NPTS + pt)*64;
    #pragma unroll
    for (int jg=0; jg<8; jg++){
        float t[8];
        #pragma unroll
        for (int i=0;i<8;i++) t[i] = b1[jg*8+i];
        #pragma unroll
        for (int k=0;k<64;k++){
            float hv = h[k];
            #pragma unroll
            for (int i=0;i<8;i++) t[i] = fmaf(hv, W1T[k*64 + jg*8 + i], t[i]);
        }
        #pragma unroll
        for (int i=0;i<8;i++) y[jg*8+i] = sc[jg*8+i] + fmaxf(t[i], 0.0f);
    }
}

// ---- pooling: wave per (b,bin); lane=channel; mean then broadcast to member points ----
__global__ void k_poolgather(const float* __restrict__ Y, const int* __restrict__ plist,
                             const int* __restrict__ binStart, const int* __restrict__ hist,
                             float* __restrict__ POOL){
    int tid = threadIdx.x; int lane = tid & 63; int wv = tid >> 6;
    int g = blockIdx.x*4 + wv;
    int b = g >> 12; int bl = g & 4095;
    int idx = b*R2 + bl;
    int start = binStart[idx]; int cnt = hist[idx];
    const int* pl = plist + b*NPTS;
    float s = 0.0f;
    for (int i=0;i<cnt;i++){
        int pt = pl[start+i];
        s += Y[((long)b*NPTS + pt)*64 + lane];
    }
    s /= fmaxf((float)cnt, 1.0f);
    for (int i=0;i<cnt;i++){
        int pt = pl[start+i];
        POOL[((long)b*NPTS + pt)*64 + lane] = s;
    }
}

// ---- fc_c: [B][N][64] -> C [B][N][256] ----
__global__ void __launch_bounds__(256) k_fc_c(const float* __restrict__ X, const float* __restrict__ WcT,
                       const float* __restrict__ bc, float* __restrict__ C){
    int pt = blockIdx.x*256 + threadIdx.x; int b = blockIdx.y; int kg = blockIdx.z;
    if (pt >= NPTS) return;
    float acc[64];
    #pragma unroll
    for (int i=0;i<64;i++) acc[i] = bc[kg*64+i];
    const float* x = X + ((long)b*NPTS + pt)*64;
    for (int kk=0;kk<64;kk+=4){
        float4 xv = *(const float4*)(x + kk);
        float vv[4] = {xv.x, xv.y, xv.z, xv.w};
        #pragma unroll
        for (int u=0;u<4;u++){
            float v = vv[u];
            const float* w = WcT + (kk+u)*256 + kg*64;
            #pragma unroll
            for (int i=0;i<64;i++) acc[i] = fmaf(v, w[i], acc[i]);
        }
    }
    float* o = C + ((long)b*NPTS + pt)*256 + kg*64;
    #pragma unroll
    for (int i=0;i<64;i+=4){
        float4 v; v.x=acc[i]; v.y=acc[i+1]; v.z=acc[i+2]; v.w=acc[i+3];
        *(float4*)(o + i) = v;
    }
}

// ---- plane scatter-mean as sorted gather -> bf16 plane [img][px][256] ----
__global__ void k_gatherC(const float* __restrict__ C, const int* __restrict__ plist,
                          const int* __restrict__ binStart, const int* __restrict__ hist,
                          ushort* __restrict__ G){
    int tid = threadIdx.x; int lane = tid & 63; int wv = tid >> 6;
    int g = blockIdx.x*4 + wv;
    int img = g >> 12; int bl = g & 4095;
    int b = img & 3;
    int idx = img*R2 + bl;
    int start = binStart[idx]; int cnt = hist[idx];
    const int* pl = plist + img*NPTS;
    float4 acc = {0.f,0.f,0.f,0.f};
    const float* Cb = C + (long)b*NPTS*256 + lane*4;
    for (int i=0;i<cnt;i++){
        int pt = pl[start+i];
        float4 v = *(const float4*)(Cb + (long)pt*256);
        acc.x += v.x; acc.y += v.y; acc.z += v.z; acc.w += v.w;
    }
    float inv = 1.0f / fmaxf((float)cnt, 1.0f);
    ushort4 o;
    o.x = f2bf(acc.x*inv); o.y = f2bf(acc.y*inv);
    o.z = f2bf(acc.z*inv); o.w = f2bf(acc.w*inv);
    *(ushort4*)(G + ((long)img*R2 + bl)*256 + lane*4) = o;
}

// ---- conv 3x3 SAME + relu as 9-tap implicit GEMM on MFMA ----
// block: one row y, all 256 ko; wave w: 64 px x ko[w*64..w*64+63]
// LDS: [3 rows][66 px][72ch pad] bf16 per 64-ci chunk
template<int OBF>
__global__ void __launch_bounds__(256) k_conv_mfma(const ushort* __restrict__ IN,
        const ushort* __restrict__ WB, const float* __restrict__ bias, void* __restrict__ OUTv){
    __shared__ __align__(16) ushort lds[3*66*72];
    int tid = threadIdx.x;
    int lane = tid & 63;
    int n0 = __builtin_amdgcn_readfirstlane((tid >> 6) * 64);
    int y = blockIdx.x;
    int img = blockIdx.y;
    const ushort* inb = IN + (long)img*4096*256;
    int m16 = lane & 15, q = lane >> 4;
    floatx4 acc[4][4];
    #pragma unroll
    for (int j=0;j<4;j++){
        float bv = bias[n0 + 16*j + m16];
        #pragma unroll
        for (int i=0;i<4;i++){ floatx4 t = {bv,bv,bv,bv}; acc[i][j] = t; }
    }
    for (int cc=0; cc<4; cc++){
        if (cc) __syncthreads();
        for (int e = tid; e < 1584; e += 256){
            int oct = e & 7;
            int col = (e >> 3) % 66;
            int row = (e >> 3) / 66;
            int gy = y + row - 1, gx = col - 1;
            uint4 v = {0u,0u,0u,0u};
            if (gy >= 0 && gy < 64 && gx >= 0 && gx < 64)
                v = *(const uint4*)(inb + ((gy*64+gx)*256 + cc*64 + oct*8));
            *(uint4*)&lds[(row*66 + col)*72 + oct*8] = v;
        }
        __syncthreads();
        #pragma unroll
        for (int tap=0; tap<9; tap++){
            int r3 = tap/3, s = tap%3;
            #pragma unroll
            for (int kc=0; kc<2; kc++){
                short8 a[4], b[4];
                #pragma unroll
                for (int j=0;j<4;j++)
                    b[j] = *(const short8*)(WB + ((long)tap*65536 + (n0+16*j+m16)*256 + cc*64 + kc*32 + q*8));
                #pragma unroll
                for (int i=0;i<4;i++)
                    a[i] = *(const short8*)&lds[(r3*66 + 16*i + m16 + s)*72 + kc*32 + q*8];
                #pragma unroll
                for (int i=0;i<4;i++)
                    #pragma unroll
                    for (int j=0;j<4;j++)
                        acc[i][j] = __builtin_amdgcn_mfma_f32_16x16x32_bf16(a[i], b[j], acc[i][j], 0, 0, 0);
            }
        }
    }
    long base = ((long)img*4096 + (long)y*64);
    #pragma unroll
    for (int i=0;i<4;i++){
        #pragma unroll
        for (int rr=0;rr<4;rr++){
            int px = 16*i + q*4 + rr;
            long rowoff = (base + px)*256;
            #pragma unroll
            for (int j=0;j<4;j++){
                float v = fmaxf(acc[i][j][rr], 0.0f);
                int ko = n0 + 16*j + m16;
                if (OBF) ((ushort*)OUTv)[rowoff + ko] = f2bf(v);
                else     ((float*) OUTv)[rowoff + ko] = v;
            }
        }
    }
}

// ---- bilinear sample (border, align_corners=False), sum 3 planes ----
__global__ void k_sample(const float* __restrict__ A2, const float* __restrict__ query,
                         float* __restrict__ out){
    int lane = threadIdx.x & 63;
    int q = blockIdx.x*4 + (threadIdx.x >> 6);
    int b = blockIdx.y;
    const float* qp = query + ((long)b*NPTS + q)*3;
    float q0 = qp[0], q1 = qp[1], q2 = qp[2];
    float a0 = 0.f, a1 = 0.f, a2v = 0.f, a3 = 0.f;
    #pragma unroll
    for (int pl = 0; pl < 3; pl++){
        float qa = (pl==2) ? q1 : q0;
        float qb = (pl==1) ? q1 : q2;
        float gx = qa*2.0f - 1.0f, gy = qb*2.0f - 1.0f;
        float xf = ((gx + 1.0f)*64.0f - 1.0f)*0.5f;
        float yf = ((gy + 1.0f)*64.0f - 1.0f)*0.5f;
        xf = fminf(fmaxf(xf, 0.0f), 63.0f);
        yf = fminf(fmaxf(yf, 0.0f), 63.0f);
        float x0f = floorf(xf), y0f = floorf(yf);
        float wx = xf - x0f, wy = yf - y0f;
        int x0 = (int)x0f, y0 = (int)y0f;
        int x1 = min(x0+1, 63), y1 = min(y0+1, 63);
        const float* base = A2 + ((long)(pl*BB+b)*R2)*256 + lane*4;
        float4 t00 = *(const float4*)(base + (long)(y0*64+x0)*256);
        float4 t01 = *(const float4*)(base + (long)(y0*64+x1)*256);
        float4 t10 = *(const float4*)(base + (long)(y1*64+x0)*256);
        float4 t11 = *(const float4*)(base + (long)(y1*64+x1)*256);
        float w00 = (1.0f-wx)*(1.0f-wy), w01 = wx*(1.0f-wy);
        float w10 = (1.0f-wx)*wy,        w11 = wx*wy;
        a0  += t00.x*w00 + t01.x*w01 + t10.x*w10 + t11.x*w11;
        a1  += t00.y*w00 + t01.y*w01 + t10.y*w10 + t11.y*w11;
        a2v += t00.z*w00 + t01.z*w01 + t10.z*w10 + t11.z*w11;
        a3  += t00.w*w00 + t01.w*w01 + t10.w*w10 + t11.w*w11;
    }
    float4 r; r.x = a0; r.y = a1; r.z = a2v; r.w = a3;
    *(float4*)(out + ((long)b*NPTS + q)*256 + lane*4) = r;
}

extern "C" void kernel_launch(void* const* d_in, const int* in_sizes, int n_in,
                              void* d_out, int out_size, void* d_ws, size_t ws_size,
                              hipStream_t stream){
    (void)in_sizes; (void)n_in; (void)out_size; (void)ws_size;
    const float* p        = (const float*)d_in[0];
    const float* query    = (const float*)d_in[1];
    const float* fc_pos_W = (const float*)d_in[2];
    const float* fc_pos_b = (const float*)d_in[3];
    const float* blk0W    = (const float*)d_in[4];
    const float* blk0b    = (const float*)d_in[5];
    const float* blk1W    = (const float*)d_in[6];
    const float* blk1b    = (const float*)d_in[7];
    const float* blkSW    = (const float*)d_in[8];
    const float* fccW     = (const float*)d_in[9];
    const float* fccB     = (const float*)d_in[10];
    const float* c1W      = (const float*)d_in[11];
    const float* c1b      = (const float*)d_in[12];
    const float* c2W      = (const float*)d_in[13];
    const float* c2b      = (const float*)d_in[14];

    char* ws = (char*)d_ws;
    size_t off = 0;
    auto alloc = [&](size_t bytes)->char*{
        char* r = ws + off; off = (off + bytes + 255) & ~(size_t)255; return r; };
    float* WposT = (float*)alloc(384*4);
    float* W0T   = (float*)alloc(24576*4);
    float* W1T   = (float*)alloc(12288*4);
    float* WsT   = (float*)alloc(24576*4);
    float* WcT   = (float*)alloc(16384*4);
    ushort* WB1  = (ushort*)alloc(589824UL*2);
    ushort* WB2  = (ushort*)alloc(589824UL*2);
    int*   IDX   = (int*)  alloc((size_t)NIMG*NPTS*4);
    int*   hist  = (int*)  alloc((size_t)NIMG*R2*4);
    int*   binStart = (int*)alloc((size_t)NIMG*R2*4);
    int*   cursor   = (int*)alloc((size_t)NIMG*R2*4);
    int*   plist    = (int*)alloc((size_t)NIMG*NPTS*4);
    // Rg packs NET0[15.36M] | POOL[7.68M] | Yb[7.68M]; C aliases the whole 30.72M
    float* Rg    = (float*)alloc(30720000UL*4);
    float* NET0  = Rg;
    float* POOL  = Rg + 15360000UL;
    float* Yb    = Rg + 23040000UL;
    float* C     = Rg;
    float* Ya    = (float*)alloc(7680000UL*4);
    ushort* G    = (ushort*)alloc(12582912UL*2);   // bf16 planes
    ushort* A1   = (ushort*)alloc(12582912UL*2);   // bf16 conv1 out
    float*  A2   = (float*) alloc(12582912UL*4);   // fp32 conv2 out

    dim3 blk(256);
    k_prep<<<4914, blk, 0, stream>>>(fc_pos_W, blk0W, blk1W, blkSW, fccW, c1W, c2W,
                                     WposT, W0T, W1T, WsT, WcT, WB1, WB2);
    k_net0<<<dim3(118, BB), blk, 0, stream>>>(p, WposT, fc_pos_b, NET0, IDX);
    // counting sort of points into bins, all 12 images
    hipMemsetAsync(hist, 0, (size_t)NIMG*R2*4, stream);
    k_hist  <<<(NIMG*NPTS + 255)/256, blk, 0, stream>>>(IDX, hist);
    k_scan  <<<NIMG, blk, 0, stream>>>(hist, binStart, cursor);
    k_mklist<<<(NIMG*NPTS + 255)/256, blk, 0, stream>>>(IDX, cursor, plist);
    // resblock 0
    k_res<<<dim3(118,BB), blk, 0, stream>>>(NET0, NET0 + 64, 128, 128,
                                            W0T, blk0b, W1T, blk1b, WsT, Ya);
    // pooling round 1 (xz bins = image b)
    k_poolgather<<<4096, blk, 0, stream>>>(Ya, plist, binStart, hist, POOL);
    k_res<<<dim3(118,BB), blk, 0, stream>>>(Ya, POOL, 64, 64,
                                            W0T + 8192, blk0b + 64, W1T + 4096, blk1b + 64,
                                            WsT + 8192, Yb);
    // pooling round 2
    k_poolgather<<<4096, blk, 0, stream>>>(Yb, plist, binStart, hist, POOL);
    k_res<<<dim3(118,BB), blk, 0, stream>>>(Yb, POOL, 64, 64,
                                            W0T + 16384, blk0b + 128, W1T + 8192, blk1b + 128,
                                            WsT + 16384, Ya);
    // fc_c -> C [B][N][256]
    k_fc_c<<<dim3(118,BB,4), blk, 0, stream>>>(Ya, WcT, fccB, C);
    // plane scatter-mean as sorted bin gather -> bf16
    k_gatherC<<<12288, blk, 0, stream>>>(C, plist, binStart, hist, G);
    // convs on MFMA (12 images; block = one row x 256 ko)
    k_conv_mfma<1><<<dim3(64,12), blk, 0, stream>>>(G,  WB1, c1b, (void*)A1);
    k_conv_mfma<0><<<dim3(64,12), blk, 0, stream>>>(A1, WB2, c2b, (void*)A2);
    // bilinear sample + plane sum
    k_sample<<<dim3(7500,BB), blk, 0, stream>>>(A2, query, (float*)d_out);
}

// Round 4
// 1133.303 us; speedup vs baseline: 7.1566x; 1.0595x over previous
//
#include <hip/hip_runtime.h>

#define NPTS 30000
#define BB 4
#define R2 4096
#define NIMG 12

typedef __attribute__((ext_vector_type(8))) short short8;
typedef __attribute__((ext_vector_type(4))) float floatx4;

__device__ __forceinline__ ushort f2bf(float x){
    union { float f; unsigned u; } v; v.f = x;
    unsigned r = (v.u + 0x7fffu + ((v.u >> 16) & 1u)) >> 16;   // RNE
    return (ushort)r;
}
__device__ __forceinline__ float bf2f(ushort u){
    union { unsigned u; float f; } v; v.u = ((unsigned)u) << 16; return v.f;
}

// ---- bin index, replicating reference fp32 op order ----
__device__ __forceinline__ int coord_bin(float v){
    float t = (v + 0.5f) / 1.100001f;
    t = fminf(fmaxf(t, 0.0f), 0.999999f);
    return (int)(t * 64.0f);
}

// ---- weight prep: MLP weights transposed fp32; conv weights -> bf16 [tap][ko][ci] ----
__global__ void k_prep(const float* __restrict__ fc_pos_W, const float* __restrict__ blk0W,
                       const float* __restrict__ blk1W, const float* __restrict__ blkSW,
                       const float* __restrict__ fccW, const float* __restrict__ c1W,
                       const float* __restrict__ c2W,
                       float* __restrict__ WposT, float* __restrict__ W0T, float* __restrict__ W1T,
                       float* __restrict__ WsT, float* __restrict__ WcT,
                       ushort* __restrict__ WB1, ushort* __restrict__ WB2){
    int t = blockIdx.x*256 + threadIdx.x;
    if (t < 384){ int d = t / 128, j = t % 128; WposT[t] = fc_pos_W[j*3 + d]; return; }
    t -= 384;
    if (t < 3*128*64){ int i = t / 8192; int r = t % 8192; int k = r / 64, j = r % 64;
        W0T[t] = blk0W[(i*64 + j)*128 + k]; return; }
    t -= 3*128*64;
    if (t < 3*64*64){ int i = t / 4096; int r = t % 4096; int k = r/64, j = r%64;
        W1T[t] = blk1W[(i*64+j)*64 + k]; return; }
    t -= 3*64*64;
    if (t < 3*128*64){ int i = t/8192; int r = t%8192; int k = r/64, j = r%64;
        WsT[t] = blkSW[(i*64+j)*128 + k]; return; }
    t -= 3*128*64;
    if (t < 64*256){ int k = t/256, j = t%256; WcT[t] = fccW[j*64 + k]; return; }
    t -= 64*256;
    if (t < 589824){ int tap = t/65536; int rem = t%65536; int ko = rem/256; int ci = rem%256;
        WB1[t] = f2bf(c1W[(ko*256+ci)*9 + tap]); return; }
    t -= 589824;
    if (t < 589824){ int tap = t/65536; int rem = t%65536; int ko = rem/256; int ci = rem%256;
        WB2[t] = f2bf(c2W[(ko*256+ci)*9 + tap]); return; }
}

// ---- fc_pos + plane indices. NET0 layout [B][N][128] (channel-last) ----
__global__ void k_net0(const float* __restrict__ p, const float* __restrict__ WposT,
                       const float* __restrict__ bpos,
                       float* __restrict__ NET0, int* __restrict__ IDX){
    int pt = blockIdx.x*256 + threadIdx.x;
    int b = blockIdx.y;
    if (pt >= NPTS) return;
    const float* pp = p + ((long)b*NPTS + pt)*3;
    float p0 = pp[0], p1 = pp[1], p2 = pp[2];
    int c0 = coord_bin(p0), c1 = coord_bin(p1), c2 = coord_bin(p2);
    IDX[(0*BB + b)*NPTS + pt] = c0 + 64*c2;   // xz
    IDX[(1*BB + b)*NPTS + pt] = c0 + 64*c1;   // xy
    IDX[(2*BB + b)*NPTS + pt] = c1 + 64*c2;   // yz
    float* out = NET0 + ((long)b*NPTS + pt)*128;
    #pragma unroll
    for (int j = 0; j < 128; j += 4){
        float4 v;
        v.x = bpos[j+0] + p0*WposT[j+0] + p1*WposT[128+j+0] + p2*WposT[256+j+0];
        v.y = bpos[j+1] + p0*WposT[j+1] + p1*WposT[128+j+1] + p2*WposT[256+j+1];
        v.z = bpos[j+2] + p0*WposT[j+2] + p1*WposT[128+j+2] + p2*WposT[256+j+2];
        v.w = bpos[j+3] + p0*WposT[j+3] + p1*WposT[128+j+3] + p2*WposT[256+j+3];
        *(float4*)(out + j) = v;
    }
}

// ---- coarse 3D bin for query spatial sort (16^3 = 4096 bins) ----
__global__ void k_qbin(const float* __restrict__ query, int* __restrict__ qIDX){
    int t = blockIdx.x*256 + threadIdx.x;
    if (t >= BB*NPTS) return;
    const float* qp = query + (long)t*3;
    int x = min((int)(fmaxf(qp[0], 0.0f)*16.0f), 15);
    int y = min((int)(fmaxf(qp[1], 0.0f)*16.0f), 15);
    int z = min((int)(fmaxf(qp[2], 0.0f)*16.0f), 15);
    qIDX[t] = (x<<8) | (y<<4) | z;
}

// ---- generic counting sort (images of NPTS entries, R2 bins each) ----
__global__ void k_hist(const int* __restrict__ IDX, int* __restrict__ hist, int n){
    int t = blockIdx.x*256 + threadIdx.x;
    if (t >= n) return;
    int img = t / NPTS;
    atomicAdd(&hist[img*R2 + IDX[t]], 1);
}

__global__ void k_scan(const int* __restrict__ hist, int* __restrict__ binStart,
                       int* __restrict__ cursor){
    __shared__ int sums[256];
    int img = blockIdx.x; int tid = threadIdx.x;
    int v[16]; int s = 0;
    const int* h = hist + img*R2 + tid*16;
    #pragma unroll
    for (int i=0;i<16;i++){ v[i] = s; s += h[i]; }
    sums[tid] = s;
    __syncthreads();
    for (int d=1; d<256; d<<=1){
        int t = (tid>=d)? sums[tid-d] : 0;
        __syncthreads();
        sums[tid] += t;
        __syncthreads();
    }
    int base = (tid==0)? 0 : sums[tid-1];
    int* bs = binStart + img*R2 + tid*16;
    int* cu = cursor  + img*R2 + tid*16;
    #pragma unroll
    for (int i=0;i<16;i++){ bs[i] = base + v[i]; cu[i] = base + v[i]; }
}

__global__ void k_mklist(const int* __restrict__ IDX, int* __restrict__ cursor,
                         int* __restrict__ plist, int n){
    int t = blockIdx.x*256 + threadIdx.x;
    if (t >= n) return;
    int img = t / NPTS; int pt = t - img*NPTS;
    int bin = IDX[t];
    int pos = atomicAdd(&cursor[img*R2 + bin], 1);
    plist[img*NPTS + pos] = pt;
}

// ---- resblock: in = concat(X1[64], X2[64]) channel-last; weights scalar-streamed ----
__global__ void __launch_bounds__(256) k_res(const float* __restrict__ X1, const float* __restrict__ X2,
                      int s1, int s2,
                      const float* __restrict__ W0T, const float* __restrict__ b0,
                      const float* __restrict__ W1T, const float* __restrict__ b1,
                      const float* __restrict__ WsT, float* __restrict__ Y){
    int pt = blockIdx.x*256 + threadIdx.x;
    int b = blockIdx.y;
    if (pt >= NPTS) return;
    float h[64], sc[64];
    #pragma unroll
    for (int j=0;j<64;j++){ h[j] = b0[j]; sc[j] = 0.0f; }
    const float* x1 = X1 + ((long)b*NPTS + pt)*s1;
    for (int kk=0;kk<64;kk+=4){
        float4 xv = *(const float4*)(x1 + kk);
        float vv[4] = {xv.x, xv.y, xv.z, xv.w};
        #pragma unroll
        for (int u=0;u<4;u++){
            float v = vv[u];
            const float* w0 = W0T + (kk+u)*64;
            const float* wsp = WsT + (kk+u)*64;
            #pragma unroll
            for (int j=0;j<64;j++){ h[j] = fmaf(v, w0[j], h[j]); sc[j] = fmaf(v, wsp[j], sc[j]); }
        }
    }
    const float* x2 = X2 + ((long)b*NPTS + pt)*s2;
    for (int kk=0;kk<64;kk+=4){
        float4 xv = *(const float4*)(x2 + kk);
        float vv[4] = {xv.x, xv.y, xv.z, xv.w};
        #pragma unroll
        for (int u=0;u<4;u++){
            float v = vv[u];
            const float* w0 = W0T + (64+kk+u)*64;
            const float* wsp = WsT + (64+kk+u)*64;
            #pragma unroll
            for (int j=0;j<64;j++){ h[j] = fmaf(v, w0[j], h[j]); sc[j] = fmaf(v, wsp[j], sc[j]); }
        }
    }
    #pragma unroll
    for (int j=0;j<64;j++) h[j] = fmaxf(h[j], 0.0f);
    float* y = Y + ((long)b*NPTS + pt)*64;
    #pragma unroll
    for (int jg=0; jg<8; jg++){
        float t[8];
        #pragma unroll
        for (int i=0;i<8;i++) t[i] = b1[jg*8+i];
        #pragma unroll
        for (int k=0;k<64;k++){
            float hv = h[k];
            #pragma unroll
            for (int i=0;i<8;i++) t[i] = fmaf(hv, W1T[k*64 + jg*8 + i], t[i]);
        }
        #pragma unroll
        for (int i=0;i<8;i++) y[jg*8+i] = sc[jg*8+i] + fmaxf(t[i], 0.0f);
    }
}

// ---- pooling: wave per (b,bin); lane=channel; mean then broadcast to member points ----
__global__ void k_poolgather(const float* __restrict__ Y, const int* __restrict__ plist,
                             const int* __restrict__ binStart, const int* __restrict__ hist,
                             float* __restrict__ POOL){
    int tid = threadIdx.x; int lane = tid & 63; int wv = tid >> 6;
    int g = blockIdx.x*4 + wv;
    int b = g >> 12; int bl = g & 4095;
    int idx = b*R2 + bl;
    int start = binStart[idx]; int cnt = hist[idx];
    const int* pl = plist + b*NPTS;
    float s = 0.0f;
    for (int i=0;i<cnt;i++){
        int pt = pl[start+i];
        s += Y[((long)b*NPTS + pt)*64 + lane];
    }
    s /= fmaxf((float)cnt, 1.0f);
    for (int i=0;i<cnt;i++){
        int pt = pl[start+i];
        POOL[((long)b*NPTS + pt)*64 + lane] = s;
    }
}

// ---- fc_c: [B][N][64] -> C [B][N][256] ----
__global__ void __launch_bounds__(256) k_fc_c(const float* __restrict__ X, const float* __restrict__ WcT,
                       const float* __restrict__ bc, float* __restrict__ C){
    int pt = blockIdx.x*256 + threadIdx.x; int b = blockIdx.y; int kg = blockIdx.z;
    if (pt >= NPTS) return;
    float acc[64];
    #pragma unroll
    for (int i=0;i<64;i++) acc[i] = bc[kg*64+i];
    const float* x = X + ((long)b*NPTS + pt)*64;
    for (int kk=0;kk<64;kk+=4){
        float4 xv = *(const float4*)(x + kk);
        float vv[4] = {xv.x, xv.y, xv.z, xv.w};
        #pragma unroll
        for (int u=0;u<4;u++){
            float v = vv[u];
            const float* w = WcT + (kk+u)*256 + kg*64;
            #pragma unroll
            for (int i=0;i<64;i++) acc[i] = fmaf(v, w[i], acc[i]);
        }
    }
    float* o = C + ((long)b*NPTS + pt)*256 + kg*64;
    #pragma unroll
    for (int i=0;i<64;i+=4){
        float4 v; v.x=acc[i]; v.y=acc[i+1]; v.z=acc[i+2]; v.w=acc[i+3];
        *(float4*)(o + i) = v;
    }
}

// ---- plane scatter-mean as sorted gather -> bf16 plane [img][px][256] ----
__global__ void k_gatherC(const float* __restrict__ C, const int* __restrict__ plist,
                          const int* __restrict__ binStart, const int* __restrict__ hist,
                          ushort* __restrict__ G){
    int tid = threadIdx.x; int lane = tid & 63; int wv = tid >> 6;
    int g = blockIdx.x*4 + wv;
    int img = g >> 12; int bl = g & 4095;
    int b = img & 3;
    int idx = img*R2 + bl;
    int start = binStart[idx]; int cnt = hist[idx];
    const int* pl = plist + img*NPTS;
    float4 acc = {0.f,0.f,0.f,0.f};
    const float* Cb = C + (long)b*NPTS*256 + lane*4;
    for (int i=0;i<cnt;i++){
        int pt = pl[start+i];
        float4 v = *(const float4*)(Cb + (long)pt*256);
        acc.x += v.x; acc.y += v.y; acc.z += v.z; acc.w += v.w;
    }
    float inv = 1.0f / fmaxf((float)cnt, 1.0f);
    ushort4 o;
    o.x = f2bf(acc.x*inv); o.y = f2bf(acc.y*inv);
    o.z = f2bf(acc.z*inv); o.w = f2bf(acc.w*inv);
    *(ushort4*)(G + ((long)img*R2 + bl)*256 + lane*4) = o;
}

// ---- conv 3x3 SAME + relu as 9-tap implicit GEMM on MFMA; bf16 out ----
__global__ void __launch_bounds__(256) k_conv_mfma(const ushort* __restrict__ IN,
        const ushort* __restrict__ WB, const float* __restrict__ bias, ushort* __restrict__ OUT){
    __shared__ __align__(16) ushort lds[3*66*72];
    int tid = threadIdx.x;
    int lane = tid & 63;
    int n0 = __builtin_amdgcn_readfirstlane((tid >> 6) * 64);
    int y = blockIdx.x;
    int img = blockIdx.y;
    const ushort* inb = IN + (long)img*4096*256;
    int m16 = lane & 15, q = lane >> 4;
    floatx4 acc[4][4];
    #pragma unroll
    for (int j=0;j<4;j++){
        float bv = bias[n0 + 16*j + m16];
        #pragma unroll
        for (int i=0;i<4;i++){ floatx4 t = {bv,bv,bv,bv}; acc[i][j] = t; }
    }
    for (int cc=0; cc<4; cc++){
        if (cc) __syncthreads();
        for (int e = tid; e < 1584; e += 256){
            int oct = e & 7;
            int col = (e >> 3) % 66;
            int row = (e >> 3) / 66;
            int gy = y + row - 1, gx = col - 1;
            uint4 v = {0u,0u,0u,0u};
            if (gy >= 0 && gy < 64 && gx >= 0 && gx < 64)
                v = *(const uint4*)(inb + ((gy*64+gx)*256 + cc*64 + oct*8));
            *(uint4*)&lds[(row*66 + col)*72 + oct*8] = v;
        }
        __syncthreads();
        #pragma unroll
        for (int tap=0; tap<9; tap++){
            int r3 = tap/3, s = tap%3;
            #pragma unroll
            for (int kc=0; kc<2; kc++){
                short8 a[4], b[4];
                #pragma unroll
                for (int j=0;j<4;j++)
                    b[j] = *(const short8*)(WB + ((long)tap*65536 + (n0+16*j+m16)*256 + cc*64 + kc*32 + q*8));
                #pragma unroll
                for (int i=0;i<4;i++)
                    a[i] = *(const short8*)&lds[(r3*66 + 16*i + m16 + s)*72 + kc*32 + q*8];
                #pragma unroll
                for (int i=0;i<4;i++)
                    #pragma unroll
                    for (int j=0;j<4;j++)
                        acc[i][j] = __builtin_amdgcn_mfma_f32_16x16x32_bf16(a[i], b[j], acc[i][j], 0, 0, 0);
            }
        }
    }
    long base = ((long)img*4096 + (long)y*64);
    #pragma unroll
    for (int i=0;i<4;i++){
        #pragma unroll
        for (int rr=0;rr<4;rr++){
            int px = 16*i + q*4 + rr;
            long rowoff = (base + px)*256;
            #pragma unroll
            for (int j=0;j<4;j++){
                float v = fmaxf(acc[i][j][rr], 0.0f);
                OUT[rowoff + n0 + 16*j + m16] = f2bf(v);
            }
        }
    }
}

// ---- bilinear sample (border, align_corners=False), sum 3 planes; bf16 planes,
//      queries processed in spatially-sorted order for L1/L2 corner reuse ----
__global__ void k_sample(const ushort* __restrict__ A2, const float* __restrict__ query,
                         const int* __restrict__ qlist, float* __restrict__ out){
    int lane = threadIdx.x & 63;
    int g = blockIdx.x*4 + (threadIdx.x >> 6);
    int b = blockIdx.y;
    int q = qlist[b*NPTS + g];
    const float* qp = query + ((long)b*NPTS + q)*3;
    float q0 = qp[0], q1 = qp[1], q2 = qp[2];
    float a0 = 0.f, a1 = 0.f, a2v = 0.f, a3 = 0.f;
    #pragma unroll
    for (int pl = 0; pl < 3; pl++){
        float qa = (pl==2) ? q1 : q0;
        float qb = (pl==1) ? q1 : q2;
        float gx = qa*2.0f - 1.0f, gy = qb*2.0f - 1.0f;
        float xf = ((gx + 1.0f)*64.0f - 1.0f)*0.5f;
        float yf = ((gy + 1.0f)*64.0f - 1.0f)*0.5f;
        xf = fminf(fmaxf(xf, 0.0f), 63.0f);
        yf = fminf(fmaxf(yf, 0.0f), 63.0f);
        float x0f = floorf(xf), y0f = floorf(yf);
        float wx = xf - x0f, wy = yf - y0f;
        int x0 = (int)x0f, y0 = (int)y0f;
        int x1 = min(x0+1, 63), y1 = min(y0+1, 63);
        const ushort* base = A2 + ((long)(pl*BB+b)*R2)*256 + lane*4;
        ushort4 t00 = *(const ushort4*)(base + (long)(y0*64+x0)*256);
        ushort4 t01 = *(const ushort4*)(base + (long)(y0*64+x1)*256);
        ushort4 t10 = *(const ushort4*)(base + (long)(y1*64+x0)*256);
        ushort4 t11 = *(const ushort4*)(base + (long)(y1*64+x1)*256);
        float w00 = (1.0f-wx)*(1.0f-wy), w01 = wx*(1.0f-wy);
        float w10 = (1.0f-wx)*wy,        w11 = wx*wy;
        a0  += bf2f(t00.x)*w00 + bf2f(t01.x)*w01 + bf2f(t10.x)*w10 + bf2f(t11.x)*w11;
        a1  += bf2f(t00.y)*w00 + bf2f(t01.y)*w01 + bf2f(t10.y)*w10 + bf2f(t11.y)*w11;
        a2v += bf2f(t00.z)*w00 + bf2f(t01.z)*w01 + bf2f(t10.z)*w10 + bf2f(t11.z)*w11;
        a3  += bf2f(t00.w)*w00 + bf2f(t01.w)*w01 + bf2f(t10.w)*w10 + bf2f(t11.w)*w11;
    }
    float4 r; r.x = a0; r.y = a1; r.z = a2v; r.w = a3;
    *(float4*)(out + ((long)b*NPTS + q)*256 + lane*4) = r;
}

extern "C" void kernel_launch(void* const* d_in, const int* in_sizes, int n_in,
                              void* d_out, int out_size, void* d_ws, size_t ws_size,
                              hipStream_t stream){
    (void)in_sizes; (void)n_in; (void)out_size; (void)ws_size;
    const float* p        = (const float*)d_in[0];
    const float* query    = (const float*)d_in[1];
    const float* fc_pos_W = (const float*)d_in[2];
    const float* fc_pos_b = (const float*)d_in[3];
    const float* blk0W    = (const float*)d_in[4];
    const float* blk0b    = (const float*)d_in[5];
    const float* blk1W    = (const float*)d_in[6];
    const float* blk1b    = (const float*)d_in[7];
    const float* blkSW    = (const float*)d_in[8];
    const float* fccW     = (const float*)d_in[9];
    const float* fccB     = (const float*)d_in[10];
    const float* c1W      = (const float*)d_in[11];
    const float* c1b      = (const float*)d_in[12];
    const float* c2W      = (const float*)d_in[13];
    const float* c2b      = (const float*)d_in[14];

    char* ws = (char*)d_ws;
    size_t off = 0;
    auto alloc = [&](size_t bytes)->char*{
        char* r = ws + off; off = (off + bytes + 255) & ~(size_t)255; return r; };
    float* WposT = (float*)alloc(384*4);
    float* W0T   = (float*)alloc(24576*4);
    float* W1T   = (float*)alloc(12288*4);
    float* WsT   = (float*)alloc(24576*4);
    float* WcT   = (float*)alloc(16384*4);
    ushort* WB1  = (ushort*)alloc(589824UL*2);
    ushort* WB2  = (ushort*)alloc(589824UL*2);
    int*   IDX   = (int*)  alloc((size_t)NIMG*NPTS*4);
    int*   qIDX  = (int*)  alloc((size_t)BB*NPTS*4);
    int*   hist  = (int*)  alloc((size_t)(NIMG+BB)*R2*4);   // hist | qhist (one memset)
    int*   qhist = hist + (size_t)NIMG*R2;
    int*   binStart = (int*)alloc((size_t)NIMG*R2*4);
    int*   cursor   = (int*)alloc((size_t)NIMG*R2*4);
    int*   plist    = (int*)alloc((size_t)NIMG*NPTS*4);
    int*   qbinStart = (int*)alloc((size_t)BB*R2*4);
    int*   qcursor   = (int*)alloc((size_t)BB*R2*4);
    int*   qlist     = (int*)alloc((size_t)BB*NPTS*4);
    // Rg packs NET0[15.36M] | POOL[7.68M] | Yb[7.68M]; C aliases the whole 30.72M
    float* Rg    = (float*)alloc(30720000UL*4);
    float* NET0  = Rg;
    float* POOL  = Rg + 15360000UL;
    float* Yb    = Rg + 23040000UL;
    float* C     = Rg;
    float* Ya    = (float*)alloc(7680000UL*4);
    ushort* G    = (ushort*)alloc(12582912UL*2);   // bf16 planes
    ushort* A1   = (ushort*)alloc(12582912UL*2);   // bf16 conv1 out
    ushort* A2   = (ushort*)alloc(12582912UL*2);   // bf16 conv2 out

    dim3 blk(256);
    k_prep<<<4914, blk, 0, stream>>>(fc_pos_W, blk0W, blk1W, blkSW, fccW, c1W, c2W,
                                     WposT, W0T, W1T, WsT, WcT, WB1, WB2);
    k_net0<<<dim3(118, BB), blk, 0, stream>>>(p, WposT, fc_pos_b, NET0, IDX);
    k_qbin<<<(BB*NPTS + 255)/256, blk, 0, stream>>>(query, qIDX);
    // counting sorts: 12 point images + 4 query batches
    hipMemsetAsync(hist, 0, (size_t)(NIMG+BB)*R2*4, stream);
    k_hist  <<<(NIMG*NPTS + 255)/256, blk, 0, stream>>>(IDX, hist, NIMG*NPTS);
    k_hist  <<<(BB*NPTS + 255)/256, blk, 0, stream>>>(qIDX, qhist, BB*NPTS);
    k_scan  <<<NIMG, blk, 0, stream>>>(hist, binStart, cursor);
    k_scan  <<<BB,   blk, 0, stream>>>(qhist, qbinStart, qcursor);
    k_mklist<<<(NIMG*NPTS + 255)/256, blk, 0, stream>>>(IDX, cursor, plist, NIMG*NPTS);
    k_mklist<<<(BB*NPTS + 255)/256, blk, 0, stream>>>(qIDX, qcursor, qlist, BB*NPTS);
    // resblock 0
    k_res<<<dim3(118,BB), blk, 0, stream>>>(NET0, NET0 + 64, 128, 128,
                                            W0T, blk0b, W1T, blk1b, WsT, Ya);
    // pooling round 1 (xz bins = image b)
    k_poolgather<<<4096, blk, 0, stream>>>(Ya, plist, binStart, hist, POOL);
    k_res<<<dim3(118,BB), blk, 0, stream>>>(Ya, POOL, 64, 64,
                                            W0T + 8192, blk0b + 64, W1T + 4096, blk1b + 64,
                                            WsT + 8192, Yb);
    // pooling round 2
    k_poolgather<<<4096, blk, 0, stream>>>(Yb, plist, binStart, hist, POOL);
    k_res<<<dim3(118,BB), blk, 0, stream>>>(Yb, POOL, 64, 64,
                                            W0T + 16384, blk0b + 128, W1T + 8192, blk1b + 128,
                                            WsT + 16384, Ya);
    // fc_c -> C [B][N][256]
    k_fc_c<<<dim3(118,BB,4), blk, 0, stream>>>(Ya, WcT, fccB, C);
    // plane scatter-mean as sorted bin gather -> bf16
    k_gatherC<<<12288, blk, 0, stream>>>(C, plist, binStart, hist, G);
    // convs on MFMA (12 images; block = one row x 256 ko); both emit bf16
    k_conv_mfma<<<dim3(64,12), blk, 0, stream>>>(G,  WB1, c1b, A1);
    k_conv_mfma<<<dim3(64,12), blk, 0, stream>>>(A1, WB2, c2b, A2);
    // bilinear sample + plane sum, spatially-sorted query order
    k_sample<<<dim3(7500,BB), blk, 0, stream>>>(A2, query, qlist, (float*)d_out);
}

// Round 5
// 673.849 us; speedup vs baseline: 12.0363x; 1.6818x over previous
//
#include <hip/hip_runtime.h>

#define NPTS 30000
#define PSTR 30208      // padded point stride (118*256), safe overreach for MFMA tiles
#define BB 4
#define R2 4096
#define NIMG 12

typedef __attribute__((ext_vector_type(8))) short short8;
typedef __attribute__((ext_vector_type(4))) float floatx4;

__device__ __forceinline__ ushort f2bf(float x){
    union { float f; unsigned u; } v; v.f = x;
    unsigned r = (v.u + 0x7fffu + ((v.u >> 16) & 1u)) >> 16;   // RNE
    return (ushort)r;
}
__device__ __forceinline__ float bf2f(ushort u){
    union { unsigned u; float f; } v; v.u = ((unsigned)u) << 16; return v.f;
}
// channel slot permutation: slot = p64(ch); inverse orig = p64i(slot)
__device__ __forceinline__ int p64i(int k){ return (k & 3)*16 + (k >> 2); }

// ---- bin index, replicating reference fp32 op order ----
__device__ __forceinline__ int coord_bin(float v){
    float t = (v + 0.5f) / 1.100001f;
    t = fminf(fmaxf(t, 0.0f), 0.999999f);
    return (int)(t * 64.0f);
}

// ---- weight prep: permuted-k bf16 weights for MFMA GEMMs ----
__global__ void k_prep(const float* __restrict__ fc_pos_W, const float* __restrict__ fc_pos_b,
                       const float* __restrict__ blk0W, const float* __restrict__ blk1W,
                       const float* __restrict__ blkSW, const float* __restrict__ fccW,
                       const float* __restrict__ c1W, const float* __restrict__ c2W,
                       float* __restrict__ WposTp, float* __restrict__ bposP,
                       ushort* __restrict__ Wcat, ushort* __restrict__ W1p,
                       ushort* __restrict__ Wcp,
                       ushort* __restrict__ WB1, ushort* __restrict__ WB2){
    int t = blockIdx.x*256 + threadIdx.x;
    if (t < 384){ int d = t/128, s = t%128;
        int j = (s<64)? p64i(s) : 64 + p64i(s-64);
        WposTp[t] = fc_pos_W[j*3 + d]; return; }
    t -= 384;
    if (t < 128){ int j = (t<64)? p64i(t) : 64 + p64i(t-64);
        bposP[t] = fc_pos_b[j]; return; }
    t -= 128;
    if (t < 49152){ // Wcat[i][n 128][k' 128]: n<64 -> W0 row n, n>=64 -> Ws row n-64
        int i = t/16384, r = t%16384, n = r/128, kp = r%128;
        int ci = (kp<64)? p64i(kp) : 64 + p64i(kp-64);
        float v = (n<64)? blk0W[(i*64+n)*128 + ci] : blkSW[(i*64+(n-64))*128 + ci];
        Wcat[t] = f2bf(v); return; }
    t -= 49152;
    if (t < 12288){ // W1p[i][n 64][k' 64]
        int i = t/4096, r = t%4096, n = r/64, kp = r%64;
        W1p[t] = f2bf(blk1W[(i*64+n)*64 + p64i(kp)]); return; }
    t -= 12288;
    if (t < 16384){ // Wcp[n 256][k' 64]
        int n = t/64, kp = t%64;
        Wcp[t] = f2bf(fccW[n*64 + p64i(kp)]); return; }
    t -= 16384;
    if (t < 589824){ // WB1[tap][ko][k' 256], k' slot of C/G
        int tap = t/65536; int rem = t%65536; int ko = rem/256; int kp = rem%256;
        int ci = 64*(kp>>6) + p64i(kp & 63);
        WB1[t] = f2bf(c1W[(ko*256+ci)*9 + tap]); return; }
    t -= 589824;
    if (t < 589824){ // WB2 natural
        int tap = t/65536; int rem = t%65536; int ko = rem/256; int ci = rem%256;
        WB2[t] = f2bf(c2W[(ko*256+ci)*9 + tap]); return; }
}

// ---- fc_pos + plane indices. NET0 bf16 [B][PSTR][128] in slot order ----
__global__ void k_net0(const float* __restrict__ p, const float* __restrict__ WposTp,
                       const float* __restrict__ bposP,
                       ushort* __restrict__ NET0, int* __restrict__ IDX){
    int pt = blockIdx.x*256 + threadIdx.x;
    int b = blockIdx.y;
    if (pt >= NPTS) return;
    const float* pp = p + ((long)b*NPTS + pt)*3;
    float p0 = pp[0], p1 = pp[1], p2 = pp[2];
    int c0 = coord_bin(p0), c1 = coord_bin(p1), c2 = coord_bin(p2);
    IDX[(0*BB + b)*NPTS + pt] = c0 + 64*c2;   // xz
    IDX[(1*BB + b)*NPTS + pt] = c0 + 64*c1;   // xy
    IDX[(2*BB + b)*NPTS + pt] = c1 + 64*c2;   // yz
    ushort* out = NET0 + ((long)b*PSTR + pt)*128;
    #pragma unroll
    for (int s = 0; s < 128; s += 4){
        ushort4 v;
        v.x = f2bf(bposP[s+0] + p0*WposTp[s+0] + p1*WposTp[128+s+0] + p2*WposTp[256+s+0]);
        v.y = f2bf(bposP[s+1] + p0*WposTp[s+1] + p1*WposTp[128+s+1] + p2*WposTp[256+s+1]);
        v.z = f2bf(bposP[s+2] + p0*WposTp[s+2] + p1*WposTp[128+s+2] + p2*WposTp[256+s+2]);
        v.w = f2bf(bposP[s+3] + p0*WposTp[s+3] + p1*WposTp[128+s+3] + p2*WposTp[256+s+3]);
        *(ushort4*)(out + s) = v;
    }
}

// ---- coarse 3D bin for query spatial sort ----
__global__ void k_qbin(const float* __restrict__ query, int* __restrict__ qIDX){
    int t = blockIdx.x*256 + threadIdx.x;
    if (t >= BB*NPTS) return;
    const float* qp = query + (long)t*3;
    int x = min((int)(fmaxf(qp[0], 0.0f)*16.0f), 15);
    int y = min((int)(fmaxf(qp[1], 0.0f)*16.0f), 15);
    int z = min((int)(fmaxf(qp[2], 0.0f)*16.0f), 15);
    qIDX[t] = (x<<8) | (y<<4) | z;
}

// ---- counting sort ----
__global__ void k_hist(const int* __restrict__ IDX, int* __restrict__ hist, int n){
    int t = blockIdx.x*256 + threadIdx.x;
    if (t >= n) return;
    int img = t / NPTS;
    atomicAdd(&hist[img*R2 + IDX[t]], 1);
}

__global__ void k_scan(const int* __restrict__ hist, int* __restrict__ binStart,
                       int* __restrict__ cursor){
    __shared__ int sums[256];
    int img = blockIdx.x; int tid = threadIdx.x;
    int v[16]; int s = 0;
    const int* h = hist + img*R2 + tid*16;
    #pragma unroll
    for (int i=0;i<16;i++){ v[i] = s; s += h[i]; }
    sums[tid] = s;
    __syncthreads();
    for (int d=1; d<256; d<<=1){
        int t = (tid>=d)? sums[tid-d] : 0;
        __syncthreads();
        sums[tid] += t;
        __syncthreads();
    }
    int base = (tid==0)? 0 : sums[tid-1];
    int* bs = binStart + img*R2 + tid*16;
    int* cu = cursor  + img*R2 + tid*16;
    #pragma unroll
    for (int i=0;i<16;i++){ bs[i] = base + v[i]; cu[i] = base + v[i]; }
}

__global__ void k_mklist(const int* __restrict__ IDX, int* __restrict__ cursor,
                         int* __restrict__ plist, int n){
    int t = blockIdx.x*256 + threadIdx.x;
    if (t >= n) return;
    int img = t / NPTS; int pt = t - img*NPTS;
    int bin = IDX[t];
    int pos = atomicAdd(&cursor[img*R2 + bin], 1);
    plist[img*NPTS + pos] = pt;
}

// ---- resblock on MFMA: wave=64 pts. GEMM1 [64x128]@[128->h64|sc64], LDS transpose,
//      GEMM2 relu(h)@W1 [64x64]; Y = sc + relu(dx), bf16 slot order ----
__global__ void __launch_bounds__(256) k_res_mfma(
        const ushort* __restrict__ X1, const ushort* __restrict__ X2, int s1, int s2,
        const ushort* __restrict__ Wcat, const float* __restrict__ b0,
        const ushort* __restrict__ W1p, const float* __restrict__ b1,
        ushort* __restrict__ Y){
    __shared__ __align__(16) ushort lds[4][64*72];
    int tid = threadIdx.x, lane = tid & 63, w = tid >> 6;
    int m16 = lane & 15, q = lane >> 4;
    int b = blockIdx.y;
    int pt0 = blockIdx.x*256 + w*64;
    const ushort* x1 = X1 + (long)b*PSTR*s1;
    const ushort* x2 = X2 + (long)b*PSTR*s2;
    floatx4 accH[4][4], accS[4][4];
    #pragma unroll
    for (int nt=0; nt<4; nt++){
        float bv = b0[nt*16 + m16];
        #pragma unroll
        for (int mt=0; mt<4; mt++){
            floatx4 t = {bv,bv,bv,bv}; accH[mt][nt] = t;
            floatx4 z = {0.f,0.f,0.f,0.f}; accS[mt][nt] = z;
        }
    }
    #pragma unroll
    for (int kk=0; kk<4; kk++){
        const ushort* xs = (kk<2)? x1 : x2;
        int st = (kk<2)? s1 : s2;
        int off = (kk&1)*32 + q*8;
        short8 a[4], bh[4], bs[4];
        #pragma unroll
        for (int mt=0; mt<4; mt++)
            a[mt] = *(const short8*)(xs + (long)(pt0 + mt*16 + m16)*st + off);
        #pragma unroll
        for (int nt=0; nt<4; nt++){
            bh[nt] = *(const short8*)(Wcat + (nt*16 + m16)*128 + kk*32 + q*8);
            bs[nt] = *(const short8*)(Wcat + ((nt+4)*16 + m16)*128 + kk*32 + q*8);
        }
        #pragma unroll
        for (int mt=0; mt<4; mt++)
            #pragma unroll
            for (int nt=0; nt<4; nt++){
                accH[mt][nt] = __builtin_amdgcn_mfma_f32_16x16x32_bf16(a[mt], bh[nt], accH[mt][nt], 0,0,0);
                accS[mt][nt] = __builtin_amdgcn_mfma_f32_16x16x32_bf16(a[mt], bs[nt], accS[mt][nt], 0,0,0);
            }
    }
    // relu(h) -> LDS in slot order (slot = m16*4 + nt, packed ushort4)
    ushort* myl = lds[w];
    #pragma unroll
    for (int mt=0; mt<4; mt++)
        #pragma unroll
        for (int r=0; r<4; r++){
            int ptl = mt*16 + q*4 + r;
            ushort4 hv;
            hv.x = f2bf(fmaxf(accH[mt][0][r], 0.0f));
            hv.y = f2bf(fmaxf(accH[mt][1][r], 0.0f));
            hv.z = f2bf(fmaxf(accH[mt][2][r], 0.0f));
            hv.w = f2bf(fmaxf(accH[mt][3][r], 0.0f));
            *(ushort4*)&myl[ptl*72 + m16*4] = hv;
        }
    // GEMM2: dx = relu(h) @ W1^T
    floatx4 accD[4][4];
    #pragma unroll
    for (int nt=0; nt<4; nt++){
        float bv = b1[nt*16 + m16];
        #pragma unroll
        for (int mt=0; mt<4; mt++){ floatx4 t = {bv,bv,bv,bv}; accD[mt][nt] = t; }
    }
    #pragma unroll
    for (int kk=0; kk<2; kk++){
        short8 a[4], bb[4];
        #pragma unroll
        for (int mt=0; mt<4; mt++)
            a[mt] = *(const short8*)&myl[(mt*16 + m16)*72 + kk*32 + q*8];
        #pragma unroll
        for (int nt=0; nt<4; nt++)
            bb[nt] = *(const short8*)(W1p + (nt*16 + m16)*64 + kk*32 + q*8);
        #pragma unroll
        for (int mt=0; mt<4; mt++)
            #pragma unroll
            for (int nt=0; nt<4; nt++)
                accD[mt][nt] = __builtin_amdgcn_mfma_f32_16x16x32_bf16(a[mt], bb[nt], accD[mt][nt], 0,0,0);
    }
    // Y = sc + relu(dx), slot-packed stores
    #pragma unroll
    for (int mt=0; mt<4; mt++)
        #pragma unroll
        for (int r=0; r<4; r++){
            int pt = pt0 + mt*16 + q*4 + r;
            if (pt < NPTS){
                ushort4 yv;
                yv.x = f2bf(accS[mt][0][r] + fmaxf(accD[mt][0][r], 0.0f));
                yv.y = f2bf(accS[mt][1][r] + fmaxf(accD[mt][1][r], 0.0f));
                yv.z = f2bf(accS[mt][2][r] + fmaxf(accD[mt][2][r], 0.0f));
                yv.w = f2bf(accS[mt][3][r] + fmaxf(accD[mt][3][r], 0.0f));
                *(ushort4*)(Y + ((long)b*PSTR + pt)*64 + m16*4) = yv;
            }
        }
}

// ---- pooling: wave per (b,bin); lane=slot; bf16 in/out, fp32 accumulate ----
__global__ void k_poolgather(const ushort* __restrict__ Y, const int* __restrict__ plist,
                             const int* __restrict__ binStart, const int* __restrict__ hist,
                             ushort* __restrict__ POOL){
    int tid = threadIdx.x; int lane = tid & 63; int wv = tid >> 6;
    int g = blockIdx.x*4 + wv;
    int b = g >> 12; int bl = g & 4095;
    int idx = b*R2 + bl;
    int start = binStart[idx]; int cnt = hist[idx];
    const int* pl = plist + b*NPTS;
    float s = 0.0f;
    for (int i=0;i<cnt;i++){
        int pt = pl[start+i];
        s += bf2f(Y[((long)b*PSTR + pt)*64 + lane]);
    }
    ushort sv = f2bf(s / fmaxf((float)cnt, 1.0f));
    for (int i=0;i<cnt;i++){
        int pt = pl[start+i];
        POOL[((long)b*PSTR + pt)*64 + lane] = sv;
    }
}

// ---- fc_c on MFMA: block = 64 pts, wave w = out ch [64w,64w+64); C bf16 slot order ----
__global__ void __launch_bounds__(256) k_fc_c_mfma(const ushort* __restrict__ X,
        const ushort* __restrict__ Wcp, const float* __restrict__ bc, ushort* __restrict__ C){
    int tid = threadIdx.x, lane = tid & 63, w = tid >> 6;
    int m16 = lane & 15, q = lane >> 4;
    int b = blockIdx.y;
    int pt0 = blockIdx.x*64;
    int n0 = w*64;
    const ushort* xb = X + (long)b*PSTR*64;
    floatx4 acc[4][4];
    #pragma unroll
    for (int nt=0; nt<4; nt++){
        float bv = bc[n0 + nt*16 + m16];
        #pragma unroll
        for (int mt=0; mt<4; mt++){ floatx4 t = {bv,bv,bv,bv}; acc[mt][nt] = t; }
    }
    #pragma unroll
    for (int kk=0; kk<2; kk++){
        short8 a[4], bb[4];
        #pragma unroll
        for (int mt=0; mt<4; mt++)
            a[mt] = *(const short8*)(xb + (long)(pt0 + mt*16 + m16)*64 + kk*32 + q*8);
        #pragma unroll
        for (int nt=0; nt<4; nt++)
            bb[nt] = *(const short8*)(Wcp + (n0 + nt*16 + m16)*64 + kk*32 + q*8);
        #pragma unroll
        for (int mt=0; mt<4; mt++)
            #pragma unroll
            for (int nt=0; nt<4; nt++)
                acc[mt][nt] = __builtin_amdgcn_mfma_f32_16x16x32_bf16(a[mt], bb[nt], acc[mt][nt], 0,0,0);
    }
    #pragma unroll
    for (int mt=0; mt<4; mt++)
        #pragma unroll
        for (int r=0; r<4; r++){
            int pt = pt0 + mt*16 + q*4 + r;
            if (pt < NPTS){
                ushort4 v;
                v.x = f2bf(acc[mt][0][r]); v.y = f2bf(acc[mt][1][r]);
                v.z = f2bf(acc[mt][2][r]); v.w = f2bf(acc[mt][3][r]);
                *(ushort4*)(C + ((long)b*PSTR + pt)*256 + n0 + m16*4) = v;
            }
        }
}

// ---- plane scatter-mean as sorted gather: bf16 C -> bf16 G (slot order kept) ----
__global__ void k_gatherC(const ushort* __restrict__ C, const int* __restrict__ plist,
                          const int* __restrict__ binStart, const int* __restrict__ hist,
                          ushort* __restrict__ G){
    int tid = threadIdx.x; int lane = tid & 63; int wv = tid >> 6;
    int g = blockIdx.x*4 + wv;
    int img = g >> 12; int bl = g & 4095;
    int b = img & 3;
    int idx = img*R2 + bl;
    int start = binStart[idx]; int cnt = hist[idx];
    const int* pl = plist + img*NPTS;
    float4 acc = {0.f,0.f,0.f,0.f};
    const ushort* Cb = C + (long)b*PSTR*256 + lane*4;
    for (int i=0;i<cnt;i++){
        int pt = pl[start+i];
        ushort4 v = *(const ushort4*)(Cb + (long)pt*256);
        acc.x += bf2f(v.x); acc.y += bf2f(v.y); acc.z += bf2f(v.z); acc.w += bf2f(v.w);
    }
    float inv = 1.0f / fmaxf((float)cnt, 1.0f);
    ushort4 o;
    o.x = f2bf(acc.x*inv); o.y = f2bf(acc.y*inv);
    o.z = f2bf(acc.z*inv); o.w = f2bf(acc.w*inv);
    *(ushort4*)(G + ((long)img*R2 + bl)*256 + lane*4) = o;
}

// ---- conv 3x3 SAME + relu as 9-tap implicit GEMM on MFMA; bf16 out ----
__global__ void __launch_bounds__(256) k_conv_mfma(const ushort* __restrict__ IN,
        const ushort* __restrict__ WB, const float* __restrict__ bias, ushort* __restrict__ OUT){
    __shared__ __align__(16) ushort lds[3*66*72];
    int tid = threadIdx.x;
    int lane = tid & 63;
    int n0 = __builtin_amdgcn_readfirstlane((tid >> 6) * 64);
    int y = blockIdx.x;
    int img = blockIdx.y;
    const ushort* inb = IN + (long)img*4096*256;
    int m16 = lane & 15, q = lane >> 4;
    floatx4 acc[4][4];
    #pragma unroll
    for (int j=0;j<4;j++){
        float bv = bias[n0 + 16*j + m16];
        #pragma unroll
        for (int i=0;i<4;i++){ floatx4 t = {bv,bv,bv,bv}; acc[i][j] = t; }
    }
    for (int cc=0; cc<4; cc++){
        if (cc) __syncthreads();
        for (int e = tid; e < 1584; e += 256){
            int oct = e & 7;
            int col = (e >> 3) % 66;
            int row = (e >> 3) / 66;
            int gy = y + row - 1, gx = col - 1;
            uint4 v = {0u,0u,0u,0u};
            if (gy >= 0 && gy < 64 && gx >= 0 && gx < 64)
                v = *(const uint4*)(inb + ((gy*64+gx)*256 + cc*64 + oct*8));
            *(uint4*)&lds[(row*66 + col)*72 + oct*8] = v;
        }
        __syncthreads();
        #pragma unroll
        for (int tap=0; tap<9; tap++){
            int r3 = tap/3, s = tap%3;
            #pragma unroll
            for (int kc=0; kc<2; kc++){
                short8 a[4], b[4];
                #pragma unroll
                for (int j=0;j<4;j++)
                    b[j] = *(const short8*)(WB + ((long)tap*65536 + (n0+16*j+m16)*256 + cc*64 + kc*32 + q*8));
                #pragma unroll
                for (int i=0;i<4;i++)
                    a[i] = *(const short8*)&lds[(r3*66 + 16*i + m16 + s)*72 + kc*32 + q*8];
                #pragma unroll
                for (int i=0;i<4;i++)
                    #pragma unroll
                    for (int j=0;j<4;j++)
                        acc[i][j] = __builtin_amdgcn_mfma_f32_16x16x32_bf16(a[i], b[j], acc[i][j], 0, 0, 0);
            }
        }
    }
    long base = ((long)img*4096 + (long)y*64);
    #pragma unroll
    for (int i=0;i<4;i++){
        #pragma unroll
        for (int rr=0;rr<4;rr++){
            int px = 16*i + q*4 + rr;
            long rowoff = (base + px)*256;
            #pragma unroll
            for (int j=0;j<4;j++){
                float v = fmaxf(acc[i][j][rr], 0.0f);
                OUT[rowoff + n0 + 16*j + m16] = f2bf(v);
            }
        }
    }
}

// ---- bilinear sample (border, align_corners=False), sum 3 planes; sorted queries ----
__global__ void k_sample(const ushort* __restrict__ A2, const float* __restrict__ query,
                         const int* __restrict__ qlist, float* __restrict__ out){
    int lane = threadIdx.x & 63;
    int g = blockIdx.x*4 + (threadIdx.x >> 6);
    int b = blockIdx.y;
    int q = qlist[b*NPTS + g];
    const float* qp = query + ((long)b*NPTS + q)*3;
    float q0 = qp[0], q1 = qp[1], q2 = qp[2];
    float a0 = 0.f, a1 = 0.f, a2v = 0.f, a3 = 0.f;
    #pragma unroll
    for (int pl = 0; pl < 3; pl++){
        float qa = (pl==2) ? q1 : q0;
        float qb = (pl==1) ? q1 : q2;
        float gx = qa*2.0f - 1.0f, gy = qb*2.0f - 1.0f;
        float xf = ((gx + 1.0f)*64.0f - 1.0f)*0.5f;
        float yf = ((gy + 1.0f)*64.0f - 1.0f)*0.5f;
        xf = fminf(fmaxf(xf, 0.0f), 63.0f);
        yf = fminf(fmaxf(yf, 0.0f), 63.0f);
        float x0f = floorf(xf), y0f = floorf(yf);
        float wx = xf - x0f, wy = yf - y0f;
        int x0 = (int)x0f, y0 = (int)y0f;
        int x1 = min(x0+1, 63), y1 = min(y0+1, 63);
        const ushort* base = A2 + ((long)(pl*BB+b)*R2)*256 + lane*4;
        ushort4 t00 = *(const ushort4*)(base + (long)(y0*64+x0)*256);
        ushort4 t01 = *(const ushort4*)(base + (long)(y0*64+x1)*256);
        ushort4 t10 = *(const ushort4*)(base + (long)(y1*64+x0)*256);
        ushort4 t11 = *(const ushort4*)(base + (long)(y1*64+x1)*256);
        float w00 = (1.0f-wx)*(1.0f-wy), w01 = wx*(1.0f-wy);
        float w10 = (1.0f-wx)*wy,        w11 = wx*wy;
        a0  += bf2f(t00.x)*w00 + bf2f(t01.x)*w01 + bf2f(t10.x)*w10 + bf2f(t11.x)*w11;
        a1  += bf2f(t00.y)*w00 + bf2f(t01.y)*w01 + bf2f(t10.y)*w10 + bf2f(t11.y)*w11;
        a2v += bf2f(t00.z)*w00 + bf2f(t01.z)*w01 + bf2f(t10.z)*w10 + bf2f(t11.z)*w11;
        a3  += bf2f(t00.w)*w00 + bf2f(t01.w)*w01 + bf2f(t10.w)*w10 + bf2f(t11.w)*w11;
    }
    float4 r; r.x = a0; r.y = a1; r.z = a2v; r.w = a3;
    *(float4*)(out + ((long)b*NPTS + q)*256 + lane*4) = r;
}

extern "C" void kernel_launch(void* const* d_in, const int* in_sizes, int n_in,
                              void* d_out, int out_size, void* d_ws, size_t ws_size,
                              hipStream_t stream){
    (void)in_sizes; (void)n_in; (void)out_size; (void)ws_size;
    const float* p        = (const float*)d_in[0];
    const float* query    = (const float*)d_in[1];
    const float* fc_pos_W = (const float*)d_in[2];
    const float* fc_pos_b = (const float*)d_in[3];
    const float* blk0W    = (const float*)d_in[4];
    const float* blk0b    = (const float*)d_in[5];
    const float* blk1W    = (const float*)d_in[6];
    const float* blk1b    = (const float*)d_in[7];
    const float* blkSW    = (const float*)d_in[8];
    const float* fccW     = (const float*)d_in[9];
    const float* fccB     = (const float*)d_in[10];
    const float* c1W      = (const float*)d_in[11];
    const float* c1b      = (const float*)d_in[12];
    const float* c2W      = (const float*)d_in[13];
    const float* c2b      = (const float*)d_in[14];

    char* ws = (char*)d_ws;
    size_t off = 0;
    auto alloc = [&](size_t bytes)->char*{
        char* r = ws + off; off = (off + bytes + 255) & ~(size_t)255; return r; };
    float* WposTp = (float*)alloc(384*4);
    float* bposP  = (float*)alloc(128*4);
    ushort* Wcat  = (ushort*)alloc(49152UL*2);
    ushort* W1p   = (ushort*)alloc(12288UL*2);
    ushort* Wcp   = (ushort*)alloc(16384UL*2);
    ushort* WB1   = (ushort*)alloc(589824UL*2);
    ushort* WB2   = (ushort*)alloc(589824UL*2);
    int*   IDX   = (int*)  alloc((size_t)NIMG*NPTS*4);
    int*   qIDX  = (int*)  alloc((size_t)BB*NPTS*4);
    int*   hist  = (int*)  alloc((size_t)(NIMG+BB)*R2*4);
    int*   qhist = hist + (size_t)NIMG*R2;
    int*   binStart = (int*)alloc((size_t)NIMG*R2*4);
    int*   cursor   = (int*)alloc((size_t)NIMG*R2*4);
    int*   plist    = (int*)alloc((size_t)NIMG*NPTS*4);
    int*   qbinStart = (int*)alloc((size_t)BB*R2*4);
    int*   qcursor   = (int*)alloc((size_t)BB*R2*4);
    int*   qlist     = (int*)alloc((size_t)BB*NPTS*4);
    ushort* NET0 = (ushort*)alloc((size_t)BB*PSTR*128*2);
    ushort* Ya   = (ushort*)alloc((size_t)BB*PSTR*64*2);
    ushort* Yb   = (ushort*)alloc((size_t)BB*PSTR*64*2);
    ushort* POOL = (ushort*)alloc((size_t)BB*PSTR*64*2);
    ushort* C    = (ushort*)alloc((size_t)BB*PSTR*256*2);
    ushort* G    = (ushort*)alloc(12582912UL*2);
    ushort* A1   = (ushort*)alloc(12582912UL*2);
    ushort* A2   = (ushort*)alloc(12582912UL*2);

    dim3 blk(256);
    k_prep<<<4914, blk, 0, stream>>>(fc_pos_W, fc_pos_b, blk0W, blk1W, blkSW, fccW, c1W, c2W,
                                     WposTp, bposP, Wcat, W1p, Wcp, WB1, WB2);
    k_net0<<<dim3(118, BB), blk, 0, stream>>>(p, WposTp, bposP, NET0, IDX);
    k_qbin<<<(BB*NPTS + 255)/256, blk, 0, stream>>>(query, qIDX);
    hipMemsetAsync(hist, 0, (size_t)(NIMG+BB)*R2*4, stream);
    k_hist  <<<(NIMG*NPTS + 255)/256, blk, 0, stream>>>(IDX, hist, NIMG*NPTS);
    k_hist  <<<(BB*NPTS + 255)/256, blk, 0, stream>>>(qIDX, qhist, BB*NPTS);
    k_scan  <<<NIMG, blk, 0, stream>>>(hist, binStart, cursor);
    k_scan  <<<BB,   blk, 0, stream>>>(qhist, qbinStart, qcursor);
    k_mklist<<<(NIMG*NPTS + 255)/256, blk, 0, stream>>>(IDX, cursor, plist, NIMG*NPTS);
    k_mklist<<<(BB*NPTS + 255)/256, blk, 0, stream>>>(qIDX, qcursor, qlist, BB*NPTS);
    // resblock 0: X1 = NET0 slots [0,64), X2 = NET0 slots [64,128)
    k_res_mfma<<<dim3(118,BB), blk, 0, stream>>>(NET0, NET0 + 64, 128, 128,
                                                 Wcat, blk0b, W1p, blk1b, Ya);
    k_poolgather<<<4096, blk, 0, stream>>>(Ya, plist, binStart, hist, POOL);
    k_res_mfma<<<dim3(118,BB), blk, 0, stream>>>(Ya, POOL, 64, 64,
                                                 Wcat + 16384, blk0b + 64, W1p + 4096, blk1b + 64, Yb);
    k_poolgather<<<4096, blk, 0, stream>>>(Yb, plist, binStart, hist, POOL);
    k_res_mfma<<<dim3(118,BB), blk, 0, stream>>>(Yb, POOL, 64, 64,
                                                 Wcat + 32768, blk0b + 128, W1p + 8192, blk1b + 128, Ya);
    // fc_c -> C bf16 [B][PSTR][256] slot order
    k_fc_c_mfma<<<dim3(469,BB), blk, 0, stream>>>(Ya, Wcp, fccB, C);
    // plane scatter-mean as sorted bin gather -> bf16 G (slot order)
    k_gatherC<<<12288, blk, 0, stream>>>(C, plist, binStart, hist, G);
    // convs on MFMA; conv1 weights k-permuted to match G slots, conv1 out natural
    k_conv_mfma<<<dim3(64,12), blk, 0, stream>>>(G,  WB1, c1b, A1);
    k_conv_mfma<<<dim3(64,12), blk, 0, stream>>>(A1, WB2, c2b, A2);
    // bilinear sample + plane sum, spatially-sorted query order
    k_sample<<<dim3(7500,BB), blk, 0, stream>>>(A2, query, qlist, (float*)d_out);
}